// Round 2
// baseline (180.913 us; speedup 1.0000x reference)
//
#include <hip/hip_runtime.h>
#include <math.h>

#define L_SEQ 384
#define E_DIM 512
#define NHEAD 8
#define NBH   16
#define HD    64
#define LOG2E 1.44269504f

typedef __attribute__((ext_vector_type(8))) __bf16 bf16x8;
typedef __attribute__((ext_vector_type(8))) _Float16 f16x8;
typedef __attribute__((ext_vector_type(4))) float f32x4;

union u4h8 { uint4 u; f16x8 h; };

__device__ __forceinline__ float uniform_f(float v) {
  return __uint_as_float(__builtin_amdgcn_readfirstlane(__float_as_uint(v)));
}

__device__ __forceinline__ unsigned f2bf(float f) {   // RNE float->bf16 bits
  unsigned u = __float_as_uint(f);
  return (u + 0x7FFFu + ((u >> 16) & 1u)) >> 16;
}

__device__ __forceinline__ unsigned ror16(unsigned x) { return (x >> 16) | (x << 16); }

__device__ __forceinline__ float dpp_xor1(float x) {  // lane e ^= 1 (quad_perm)
  return __int_as_float(__builtin_amdgcn_mov_dpp(__float_as_int(x), 0xB1, 0xF, 0xF, 0));
}
__device__ __forceinline__ float dpp_xor2(float x) {  // lane e ^= 2
  return __int_as_float(__builtin_amdgcn_mov_dpp(__float_as_int(x), 0x4E, 0xF, 0xF, 0));
}
template <int IMM>
__device__ __forceinline__ float swz_xor(float x) {   // ds_swizzle: imm must be literal
  return __int_as_float(__builtin_amdgcn_ds_swizzle(__float_as_int(x), IMM));
}

// ---------------------------------------------------------------------------
// Convert x|Wq|Wk|Wv (contiguous dst1) and Wo (dst2) to bf16 (R5-proven).
// ---------------------------------------------------------------------------
__global__ __launch_bounds__(256) void to_bf16_all(
    const float* __restrict__ x, const float* __restrict__ Wq,
    const float* __restrict__ Wk, const float* __restrict__ Wv,
    const float* __restrict__ Wo, unsigned short* __restrict__ dst1,
    unsigned short* __restrict__ dst2)
{
  int e0 = (blockIdx.x * 256 + threadIdx.x) * 4;
  if (e0 >= 1441792) return;
  const float* src; unsigned short* d; int s;
  if (e0 < 393216)       { src = x;  s = e0;           d = dst1 + e0; }
  else if (e0 < 655360)  { src = Wq; s = e0 - 393216;  d = dst1 + e0; }
  else if (e0 < 917504)  { src = Wk; s = e0 - 655360;  d = dst1 + e0; }
  else if (e0 < 1179648) { src = Wv; s = e0 - 917504;  d = dst1 + e0; }
  else                   { src = Wo; s = e0 - 1179648; d = dst2 + s;  }
  float4 v = *(const float4*)(src + s);
  unsigned lo = f2bf(v.x) | (f2bf(v.y) << 16);
  unsigned hi = f2bf(v.z) | (f2bf(v.w) << 16);
  *(uint2*)d = make_uint2(lo, hi);
}

// ---------------------------------------------------------------------------
// Pure-bf16 MFMA GEMM (R5-proven). C = A @ B^T.
// Block 256 = 4 waves; tile 64x64; wave = 16-row strip, 4 n-tiles.
// mode 0: C[m*N+f]; mode 1: head-scatter C[((b*8+h)*L+l)*64+d].
// ---------------------------------------------------------------------------
__global__ __launch_bounds__(256) void gemm_mfma(
    const __bf16* __restrict__ A, const __bf16* __restrict__ B0,
    const __bf16* __restrict__ B1, const __bf16* __restrict__ B2,
    float* __restrict__ C0, float* __restrict__ C1, float* __restrict__ C2,
    int M, int N, int K, int mode)
{
  const int z = blockIdx.z;
  const __bf16* Bm = (z == 0) ? B0 : (z == 1) ? B1 : B2;
  float* Cp = (z == 0) ? C0 : (z == 1) ? C1 : C2;

  const int tid = threadIdx.x;
  const int wave = tid >> 6, lane = tid & 63;
  const int m0 = blockIdx.y * 64 + wave * 16;
  const int n0 = blockIdx.x * 64;
  const int mr = lane & 15, quad = lane >> 4;

  f32x4 acc[4];
  #pragma unroll
  for (int nt = 0; nt < 4; ++nt) acc[nt] = (f32x4){0.f, 0.f, 0.f, 0.f};

  const __bf16* ap = A + (size_t)(m0 + mr) * K + quad * 8;
  const __bf16* bp = Bm + (size_t)(n0 + mr) * K + quad * 8;

  #pragma unroll 4
  for (int k0 = 0; k0 < K; k0 += 32) {
    bf16x8 a = *(const bf16x8*)(ap + k0);
    #pragma unroll
    for (int nt = 0; nt < 4; ++nt) {
      bf16x8 b = *(const bf16x8*)(bp + (size_t)nt * 16 * K + k0);
      acc[nt] = __builtin_amdgcn_mfma_f32_16x16x32_bf16(a, b, acc[nt], 0, 0, 0);
    }
  }

  #pragma unroll
  for (int nt = 0; nt < 4; ++nt) {
    int n = n0 + nt * 16 + mr;
    #pragma unroll
    for (int r = 0; r < 4; ++r) {
      int m = m0 + quad * 4 + r;
      if (mode == 0) {
        Cp[(size_t)m * N + n] = acc[nt][r];
      } else {
        int b = m / L_SEQ, l = m % L_SEQ;
        int h = n >> 6, d = n & 63;
        Cp[((size_t)(b * NHEAD + h) * L_SEQ + l) * HD + d] = acc[nt][r];
      }
    }
  }
}

// ---------------------------------------------------------------------------
// prep_norm_z: per-atom normalize Q,K -> f16 qhat/khat; build shared PV
// operand Z0[bh][col=(a,b,e)][j] = khat_b(j,a) * v_e(j,a)  (f16).
// |ham(q,k)| = |q||k| lets normalization hoist out of the pairwise core.
// grid (6 l-blocks, 4 a-groups, 16 bh) x 256; wave = 64 consecutive l
// (same a) so Z stores are 128B-contiguous per instr.
// ---------------------------------------------------------------------------
__global__ __launch_bounds__(256) void prep_norm_z(
    const float* __restrict__ Qw, const float* __restrict__ Kw,
    const float* __restrict__ Vw, _Float16* __restrict__ qhh,
    _Float16* __restrict__ khh, _Float16* __restrict__ Z0)
{
  const int tid = threadIdx.x;
  const int l = blockIdx.x * 64 + (tid & 63);
  const int a = blockIdx.y * 4 + (tid >> 6);
  const int bh = blockIdx.z;
  const size_t base = ((size_t)(bh * L_SEQ + l)) * HD + a * 4;

  float4 qq = *(const float4*)(Qw + base);
  float dq = qq.x*qq.x + qq.y*qq.y + qq.z*qq.z + qq.w*qq.w;
  float rq = __builtin_amdgcn_rsqf(fmaxf(dq, 1e-30f));
  float4 kq = *(const float4*)(Kw + base);
  float dk = kq.x*kq.x + kq.y*kq.y + kq.z*kq.z + kq.w*kq.w;
  float rk = __builtin_amdgcn_rsqf(fmaxf(dk, 1e-30f));
  float4 vq = *(const float4*)(Vw + base);

  union { _Float16 h[4]; uint2 u; } pq, pk;
  pq.h[0] = (_Float16)(qq.x * rq); pq.h[1] = (_Float16)(qq.y * rq);
  pq.h[2] = (_Float16)(qq.z * rq); pq.h[3] = (_Float16)(qq.w * rq);
  float kb0 = kq.x * rk, kb1 = kq.y * rk, kb2 = kq.z * rk, kb3 = kq.w * rk;
  pk.h[0] = (_Float16)kb0; pk.h[1] = (_Float16)kb1;
  pk.h[2] = (_Float16)kb2; pk.h[3] = (_Float16)kb3;
  *(uint2*)(qhh + base) = pq.u;
  *(uint2*)(khh + base) = pk.u;

  float kb[4] = {kb0, kb1, kb2, kb3};
  float ve[4] = {vq.x, vq.y, vq.z, vq.w};
  _Float16* zp = Z0 + ((size_t)(bh * 256 + a * 16)) * L_SEQ + l;
  #pragma unroll
  for (int b = 0; b < 4; ++b)
    #pragma unroll
    for (int e = 0; e < 4; ++e)
      zp[(size_t)(b * 4 + e) * L_SEQ] = (_Float16)(kb[b] * ve[e]);
}

// ---------------------------------------------------------------------------
// score_gate: S_c[i,j] = sum_t R_c(qhat)[i,t]*khat[j,t] via MFMA (K=64),
// then gate G_c = sigmoid(sum_p w[c][p]*S_p/16 + b[c]) -> f16.
// The 4 R_c A-fragments are built in-register from one qhat fragment:
// R_c[b] = sgn_c(b)*qhat[b^c]  (half-swap via ror16 + sign XOR on f16 pairs).
// grid (6 j-tiles, 6 i-tiles, 16 bh) x 256; tile 64x64; 32 MFMA/wave.
// ---------------------------------------------------------------------------
__global__ __launch_bounds__(256) void score_gate(
    const _Float16* __restrict__ qhh, const _Float16* __restrict__ khh,
    const float* __restrict__ dde_w, const float* __restrict__ dde_b,
    _Float16* __restrict__ G)
{
  const int tid = threadIdx.x, wave = tid >> 6, lane = tid & 63;
  const int mr = lane & 15, quad = lane >> 4;
  const int bh = blockIdx.z;
  const int i0 = blockIdx.y * 64 + wave * 16;
  const int j0 = blockIdx.x * 64;

  float wn[16], bn[4];
  #pragma unroll
  for (int t = 0; t < 16; ++t) wn[t] = uniform_f(dde_w[t]) * (-LOG2E * 0.0625f);
  #pragma unroll
  for (int c = 0; c < 4; ++c) bn[c] = uniform_f(dde_b[c]) * (-LOG2E);

  f32x4 acc[4][4];   // [c][nt]
  #pragma unroll
  for (int c = 0; c < 4; ++c)
    #pragma unroll
    for (int nt = 0; nt < 4; ++nt) acc[c][nt] = (f32x4){0.f, 0.f, 0.f, 0.f};

  const _Float16* ap = qhh + ((size_t)(bh * L_SEQ + i0 + mr)) * HD + quad * 8;
  const _Float16* bp = khh + ((size_t)(bh * L_SEQ + j0 + mr)) * HD + quad * 8;

  #pragma unroll
  for (int ks = 0; ks < 2; ++ks) {
    uint4 qa = *(const uint4*)(ap + ks * 32);   // 2 atoms: [w|x][y|z][w'|x'][y'|z']
    unsigned s0 = ror16(qa.x), s1 = ror16(qa.y), s2 = ror16(qa.z), s3 = ror16(qa.w);
    u4h8 fr[4];
    // R0=(w,-x,-y,-z)  R1=(x,w,-z,y)  R2=(y,z,w,-x)  R3=(z,-y,x,w)
    fr[0].u = make_uint4(qa.x ^ 0x80000000u, qa.y ^ 0x80008000u,
                         qa.z ^ 0x80000000u, qa.w ^ 0x80008000u);
    fr[1].u = make_uint4(s0, s1 ^ 0x00008000u, s2, s3 ^ 0x00008000u);
    fr[2].u = make_uint4(qa.y, qa.x ^ 0x80000000u, qa.w, qa.z ^ 0x80000000u);
    fr[3].u = make_uint4(s1 ^ 0x80000000u, s0, s3 ^ 0x80000000u, s2);
    #pragma unroll
    for (int nt = 0; nt < 4; ++nt) {
      u4h8 bb; bb.h = *(const f16x8*)(bp + (size_t)nt * 16 * HD + ks * 32);
      #pragma unroll
      for (int c = 0; c < 4; ++c)
        acc[c][nt] = __builtin_amdgcn_mfma_f32_16x16x32_f16(fr[c].h, bb.h, acc[c][nt], 0, 0, 0);
    }
  }

  #pragma unroll
  for (int nt = 0; nt < 4; ++nt) {
    const int j = j0 + nt * 16 + mr;
    #pragma unroll
    for (int r = 0; r < 4; ++r) {
      const int i = i0 + quad * 4 + r;
      float S0 = acc[0][nt][r], S1 = acc[1][nt][r];
      float S2 = acc[2][nt][r], S3 = acc[3][nt][r];
      #pragma unroll
      for (int c = 0; c < 4; ++c) {
        float n = bn[c] + wn[c*4+0]*S0 + wn[c*4+1]*S1 + wn[c*4+2]*S2 + wn[c*4+3]*S3;
        float g = __builtin_amdgcn_rcpf(1.f + __builtin_amdgcn_exp2f(n));
        G[((size_t)(c * NBH + bh) * L_SEQ + i) * L_SEQ + j] = (_Float16)g;
      }
    }
  }
}

// ---------------------------------------------------------------------------
// pv_combine: ACC_c = G_c @ Z0 (MFMA, K=384), then
//   ctx_d(i,a) = sum_{c,b} sgn_c(b)*qhat[i,a,b^c]*sigma(c,d)*ACC_c[i,(a,b,c^d)]
// done per-lane (lane mr: b=mr>>2, e=mr&3) with Klein-group identities
// (pi_c(e)=c^e), then XOR-butterfly: b-reduce (swizzle x4,x8) + permuted
// e-stages (dpp x1,x2 with c<->c^1 / c<->c^2 pairing) puts T_d = ctx_d in
// register r_{d^e}; lane e=0 stores bf16 directly to CTXB (no slab reduce).
// grid (4 col-groups, 6 i-tiles, 16 bh) x 256; 192 MFMA/wave.
// ---------------------------------------------------------------------------
__global__ __launch_bounds__(256) void pv_combine(
    const _Float16* __restrict__ G, const _Float16* __restrict__ Z0,
    const _Float16* __restrict__ qhh, unsigned short* __restrict__ CTXB)
{
  __shared__ float qs[64][17];   // +1 pad: avoid 4-way quad bank collision
  const int tid = threadIdx.x, wave = tid >> 6, lane = tid & 63;
  const int mr = lane & 15, quad = lane >> 4;
  const int bh = blockIdx.z;
  const int i0 = blockIdx.y * 64;
  const int cg = blockIdx.x;

  {  // stage qhat (f32) for this i-tile x col-group: 64 i x 16 t
    int il = tid >> 2, t0 = (tid & 3) * 4;
    const _Float16* qp = qhh + ((size_t)(bh * L_SEQ + i0 + il)) * HD + cg * 16 + t0;
    union { uint2 u; _Float16 h[4]; } cv; cv.u = *(const uint2*)qp;
    qs[il][t0 + 0] = (float)cv.h[0]; qs[il][t0 + 1] = (float)cv.h[1];
    qs[il][t0 + 2] = (float)cv.h[2]; qs[il][t0 + 3] = (float)cv.h[3];
  }
  __syncthreads();

  const int bq = mr >> 2, e = mr & 3;
  // sgn_c(b) neg-bits over b; tau(c,e)=sigma(c,c^e) neg-bits over e
  const unsigned sgnb[4] = {0xEu, 0x4u, 0x8u, 0x2u};
  const unsigned taub[4] = {0x0u, 0xAu, 0x6u, 0xCu};
  unsigned msk[4];
  #pragma unroll
  for (int c = 0; c < 4; ++c)
    msk[c] = ((((sgnb[c] >> bq) & 1u) ^ ((taub[c] >> e) & 1u)) << 31);

  float p[4][4][4];  // [c][nt][r], statically indexed (fully unrolled)

  const _Float16* bpz = Z0 + ((size_t)(bh * 256 + cg * 64 + mr)) * L_SEQ + quad * 8;

  #pragma unroll
  for (int c = 0; c < 4; ++c) {
    f32x4 acc[4];
    #pragma unroll
    for (int nt = 0; nt < 4; ++nt) acc[nt] = (f32x4){0.f, 0.f, 0.f, 0.f};
    const _Float16* apg = G +
        ((size_t)(c * NBH + bh) * L_SEQ + i0 + wave * 16 + mr) * L_SEQ + quad * 8;
    #pragma unroll 4
    for (int k0 = 0; k0 < L_SEQ; k0 += 32) {
      u4h8 aa; aa.h = *(const f16x8*)(apg + k0);
      #pragma unroll
      for (int nt = 0; nt < 4; ++nt) {
        u4h8 bb; bb.h = *(const f16x8*)(bpz + (size_t)nt * 16 * L_SEQ + k0);
        acc[nt] = __builtin_amdgcn_mfma_f32_16x16x32_f16(aa.h, bb.h, acc[nt], 0, 0, 0);
      }
    }
    #pragma unroll
    for (int nt = 0; nt < 4; ++nt)
      #pragma unroll
      for (int r = 0; r < 4; ++r) {
        int il = wave * 16 + quad * 4 + r;
        float sq = __uint_as_float(__float_as_uint(qs[il][nt * 4 + (bq ^ c)]) ^ msk[c]);
        p[c][nt][r] = sq * acc[nt][r];
      }
  }

  const int bb_ = bh >> 3, hh = bh & 7;
  #pragma unroll
  for (int nt = 0; nt < 4; ++nt) {
    #pragma unroll
    for (int r = 0; r < 4; ++r) {
      float pb[4];
      #pragma unroll
      for (int c = 0; c < 4; ++c) {           // b-reduce: lanes mr^4, mr^8
        float v = p[c][nt][r];
        v += swz_xor<0x101F>(v);
        v += swz_xor<0x201F>(v);
        pb[c] = v;
      }
      // permuted e-stages: after these, reg r_c holds T_{c^e}
      float q0 = pb[0] + dpp_xor1(pb[1]);
      float q1 = pb[1] + dpp_xor1(pb[0]);
      float q2 = pb[2] + dpp_xor1(pb[3]);
      float q3 = pb[3] + dpp_xor1(pb[2]);
      float r0 = q0 + dpp_xor2(q2);
      float r1 = q1 + dpp_xor2(q3);
      float r2 = q2 + dpp_xor2(q0);
      float r3 = q3 + dpp_xor2(q1);
      if (mr == 0) {                          // lane e=0,b=0: r_c = ctx_c
        int i = i0 + wave * 16 + quad * 4 + r;
        unsigned lo = f2bf(r0) | (f2bf(r1) << 16);
        unsigned hi = f2bf(r2) | (f2bf(r3) << 16);
        *(uint2*)&CTXB[((size_t)(bb_ * L_SEQ + i) * E_DIM) + hh * HD + (cg * 4 + nt) * 4] =
            make_uint2(lo, hi);
      }
    }
  }
}

// ---------------------------------------------------------------------------
// Workspace (max 24,117,248 B <= prior 24,379,392 footprint):
//   [0        ..   524288)  Wob bf16                       [whole run]
//   [524288   ..  1310720)  qhat f16                       [prep -> pv]
//   [1310720  ..  4456448)  Z0 f16                         [prep -> pv]
//   [4456448  ..  5242880)  khat f16 [prep->gate] | CTXB bf16 [pv->out]
//   [5242880  .. 24117248)  G f16 [gate -> pv]
//     overlays (dead before G written):
//     [5242880 ..  9961472)  Qw|Kw|Vw fp32                 [gemm -> prep]
//     [9961472 .. 12320768)  xb|Wqb|Wkb|Wvb bf16           [cvt -> gemm]
// ---------------------------------------------------------------------------
extern "C" void kernel_launch(void* const* d_in, const int* in_sizes, int n_in,
                              void* d_out, int out_size, void* d_ws, size_t ws_size,
                              hipStream_t stream)
{
  const float* x     = (const float*)d_in[0];
  const float* Wq    = (const float*)d_in[1];
  const float* Wk    = (const float*)d_in[2];
  const float* Wv    = (const float*)d_in[3];
  const float* Wo    = (const float*)d_in[4];
  const float* dde_w = (const float*)d_in[5];
  const float* dde_b = (const float*)d_in[6];
  float* out = (float*)d_out;

  char* ws = (char*)d_ws;
  unsigned short* Wob  = (unsigned short*)(ws + 0);
  _Float16* qhh = (_Float16*)(ws + 524288);
  _Float16* Z0h = (_Float16*)(ws + 1310720);
  _Float16* khh = (_Float16*)(ws + 4456448);
  unsigned short* CTXB = (unsigned short*)(ws + 4456448);
  _Float16* Gh  = (_Float16*)(ws + 5242880);
  float* Qw = (float*)(ws + 5242880);
  float* Kw = (float*)(ws + 6815744);
  float* Vw = (float*)(ws + 8388608);
  unsigned short* xb = (unsigned short*)(ws + 9961472);
  unsigned short* Wqb = (unsigned short*)(ws + 10747904);
  unsigned short* Wkb = (unsigned short*)(ws + 11272192);
  unsigned short* Wvb = (unsigned short*)(ws + 11796480);

  // 1) fp32 -> bf16 conversions
  to_bf16_all<<<1408, 256, 0, stream>>>(x, Wq, Wk, Wv, Wo, xb, Wob);

  // 2) Q/K/V projections: bf16 MFMA, head-scatter fp32 epilogue
  gemm_mfma<<<dim3(8, 12, 3), 256, 0, stream>>>(
      (const __bf16*)xb, (const __bf16*)Wqb, (const __bf16*)Wkb, (const __bf16*)Wvb,
      Qw, Kw, Vw, 2 * L_SEQ, E_DIM, E_DIM, 1);

  // 3) normalize + build qhat/khat f16 and shared PV operand Z0
  prep_norm_z<<<dim3(6, 4, 16), 256, 0, stream>>>(Qw, Kw, Vw, qhh, khh, Z0h);

  // 4) score GEMMs (in-register R_c fragments) + fused gate -> G f16
  score_gate<<<dim3(6, 6, 16), 256, 0, stream>>>(qhh, khh, dde_w, dde_b, Gh);

  // 5) PV GEMMs + Klein-butterfly combine -> CTXB bf16 (no slab reduce)
  pv_combine<<<dim3(4, 6, 16), 256, 0, stream>>>(Gh, Z0h, qhh, CTXB);

  // 6) output projection: bf16 MFMA, fp32 out
  gemm_mfma<<<dim3(8, 12, 1), 256, 0, stream>>>(
      (const __bf16*)CTXB, (const __bf16*)Wob, nullptr, nullptr,
      out, nullptr, nullptr, 2 * L_SEQ, E_DIM, E_DIM, 0);
}

// Round 3
// 165.789 us; speedup vs baseline: 1.0912x; 1.0912x over previous
//
#include <hip/hip_runtime.h>
#include <math.h>

#define L_SEQ 384
#define E_DIM 512
#define NHEAD 8
#define NBH   16
#define HD    64
#define LOG2E 1.44269504f

typedef __attribute__((ext_vector_type(8))) __bf16 bf16x8;
typedef __attribute__((ext_vector_type(8))) _Float16 f16x8;
typedef __attribute__((ext_vector_type(4))) float f32x4;

union u4h8 { uint4 u; f16x8 h; };

__device__ __forceinline__ float uniform_f(float v) {
  return __uint_as_float(__builtin_amdgcn_readfirstlane(__float_as_uint(v)));
}

__device__ __forceinline__ unsigned f2bf(float f) {   // RNE float->bf16 bits
  unsigned u = __float_as_uint(f);
  return (u + 0x7FFFu + ((u >> 16) & 1u)) >> 16;
}

__device__ __forceinline__ unsigned ror16(unsigned x) { return (x >> 16) | (x << 16); }

template <int IMM>
__device__ __forceinline__ float swz_xor(float x) {   // ds_swizzle: imm must be literal
  return __int_as_float(__builtin_amdgcn_ds_swizzle(__float_as_int(x), IMM));
}

// ---------------------------------------------------------------------------
// Convert x|Wq|Wk|Wv (contiguous dst1) and Wo (dst2) to bf16 (R5-proven).
// ---------------------------------------------------------------------------
__global__ __launch_bounds__(256) void to_bf16_all(
    const float* __restrict__ x, const float* __restrict__ Wq,
    const float* __restrict__ Wk, const float* __restrict__ Wv,
    const float* __restrict__ Wo, unsigned short* __restrict__ dst1,
    unsigned short* __restrict__ dst2)
{
  int e0 = (blockIdx.x * 256 + threadIdx.x) * 4;
  if (e0 >= 1441792) return;
  const float* src; unsigned short* d; int s;
  if (e0 < 393216)       { src = x;  s = e0;           d = dst1 + e0; }
  else if (e0 < 655360)  { src = Wq; s = e0 - 393216;  d = dst1 + e0; }
  else if (e0 < 917504)  { src = Wk; s = e0 - 655360;  d = dst1 + e0; }
  else if (e0 < 1179648) { src = Wv; s = e0 - 917504;  d = dst1 + e0; }
  else                   { src = Wo; s = e0 - 1179648; d = dst2 + s;  }
  float4 v = *(const float4*)(src + s);
  unsigned lo = f2bf(v.x) | (f2bf(v.y) << 16);
  unsigned hi = f2bf(v.z) | (f2bf(v.w) << 16);
  *(uint2*)d = make_uint2(lo, hi);
}

// ---------------------------------------------------------------------------
// Pure-bf16 MFMA GEMM (R5-proven). C = A @ B^T.
// Block 256 = 4 waves; tile 64x64; wave = 16-row strip, 4 n-tiles.
// mode 0: C[m*N+f]; mode 1: head-scatter C[((b*8+h)*L+l)*64+d].
// ---------------------------------------------------------------------------
__global__ __launch_bounds__(256) void gemm_mfma(
    const __bf16* __restrict__ A, const __bf16* __restrict__ B0,
    const __bf16* __restrict__ B1, const __bf16* __restrict__ B2,
    float* __restrict__ C0, float* __restrict__ C1, float* __restrict__ C2,
    int M, int N, int K, int mode)
{
  const int z = blockIdx.z;
  const __bf16* Bm = (z == 0) ? B0 : (z == 1) ? B1 : B2;
  float* Cp = (z == 0) ? C0 : (z == 1) ? C1 : C2;

  const int tid = threadIdx.x;
  const int wave = tid >> 6, lane = tid & 63;
  const int m0 = blockIdx.y * 64 + wave * 16;
  const int n0 = blockIdx.x * 64;
  const int mr = lane & 15, quad = lane >> 4;

  f32x4 acc[4];
  #pragma unroll
  for (int nt = 0; nt < 4; ++nt) acc[nt] = (f32x4){0.f, 0.f, 0.f, 0.f};

  const __bf16* ap = A + (size_t)(m0 + mr) * K + quad * 8;
  const __bf16* bp = Bm + (size_t)(n0 + mr) * K + quad * 8;

  #pragma unroll 4
  for (int k0 = 0; k0 < K; k0 += 32) {
    bf16x8 a = *(const bf16x8*)(ap + k0);
    #pragma unroll
    for (int nt = 0; nt < 4; ++nt) {
      bf16x8 b = *(const bf16x8*)(bp + (size_t)nt * 16 * K + k0);
      acc[nt] = __builtin_amdgcn_mfma_f32_16x16x32_bf16(a, b, acc[nt], 0, 0, 0);
    }
  }

  #pragma unroll
  for (int nt = 0; nt < 4; ++nt) {
    int n = n0 + nt * 16 + mr;
    #pragma unroll
    for (int r = 0; r < 4; ++r) {
      int m = m0 + quad * 4 + r;
      if (mode == 0) {
        Cp[(size_t)m * N + n] = acc[nt][r];
      } else {
        int b = m / L_SEQ, l = m % L_SEQ;
        int h = n >> 6, d = n & 63;
        Cp[((size_t)(b * NHEAD + h) * L_SEQ + l) * HD + d] = acc[nt][r];
      }
    }
  }
}

// ---------------------------------------------------------------------------
// prep_norm_z: per-atom normalize Q,K -> f16 qhat/khat; build shared PV
// operand Z0[bh][col=(a,b,e)][j] = khat_b(j,a) * v_e(j,a)  (f16).
// grid (6 l-blocks, 4 a-groups, 16 bh) x 256.
// ---------------------------------------------------------------------------
__global__ __launch_bounds__(256) void prep_norm_z(
    const float* __restrict__ Qw, const float* __restrict__ Kw,
    const float* __restrict__ Vw, _Float16* __restrict__ qhh,
    _Float16* __restrict__ khh, _Float16* __restrict__ Z0)
{
  const int tid = threadIdx.x;
  const int l = blockIdx.x * 64 + (tid & 63);
  const int a = blockIdx.y * 4 + (tid >> 6);
  const int bh = blockIdx.z;
  const size_t base = ((size_t)(bh * L_SEQ + l)) * HD + a * 4;

  float4 qq = *(const float4*)(Qw + base);
  float dq = qq.x*qq.x + qq.y*qq.y + qq.z*qq.z + qq.w*qq.w;
  float rq = __builtin_amdgcn_rsqf(fmaxf(dq, 1e-30f));
  float4 kq = *(const float4*)(Kw + base);
  float dk = kq.x*kq.x + kq.y*kq.y + kq.z*kq.z + kq.w*kq.w;
  float rk = __builtin_amdgcn_rsqf(fmaxf(dk, 1e-30f));
  float4 vq = *(const float4*)(Vw + base);

  union { _Float16 h[4]; uint2 u; } pq, pk;
  pq.h[0] = (_Float16)(qq.x * rq); pq.h[1] = (_Float16)(qq.y * rq);
  pq.h[2] = (_Float16)(qq.z * rq); pq.h[3] = (_Float16)(qq.w * rq);
  float kb0 = kq.x * rk, kb1 = kq.y * rk, kb2 = kq.z * rk, kb3 = kq.w * rk;
  pk.h[0] = (_Float16)kb0; pk.h[1] = (_Float16)kb1;
  pk.h[2] = (_Float16)kb2; pk.h[3] = (_Float16)kb3;
  *(uint2*)(qhh + base) = pq.u;
  *(uint2*)(khh + base) = pk.u;

  float kb[4] = {kb0, kb1, kb2, kb3};
  float ve[4] = {vq.x, vq.y, vq.z, vq.w};
  _Float16* zp = Z0 + ((size_t)(bh * 256 + a * 16)) * L_SEQ + l;
  #pragma unroll
  for (int b = 0; b < 4; ++b)
    #pragma unroll
    for (int e = 0; e < 4; ++e)
      zp[(size_t)(b * 4 + e) * L_SEQ] = (_Float16)(kb[b] * ve[e]);
}

// ---------------------------------------------------------------------------
// score_gate: S_c[i,j] = sum_t R_c(qhat)[i,t]*khat[j,t] via MFMA (K=64),
// then gate G_c = sigmoid(sum_p w[c][p]*S_p/16 + b[c]) -> f16.
// grid (6 j-tiles, 6 i-tiles, 16 bh) x 256; tile 64x64; 32 MFMA/wave.
// ---------------------------------------------------------------------------
__global__ __launch_bounds__(256) void score_gate(
    const _Float16* __restrict__ qhh, const _Float16* __restrict__ khh,
    const float* __restrict__ dde_w, const float* __restrict__ dde_b,
    _Float16* __restrict__ G)
{
  const int tid = threadIdx.x, wave = tid >> 6, lane = tid & 63;
  const int mr = lane & 15, quad = lane >> 4;
  const int bh = blockIdx.z;
  const int i0 = blockIdx.y * 64 + wave * 16;
  const int j0 = blockIdx.x * 64;

  float wn[16], bn[4];
  #pragma unroll
  for (int t = 0; t < 16; ++t) wn[t] = uniform_f(dde_w[t]) * (-LOG2E * 0.0625f);
  #pragma unroll
  for (int c = 0; c < 4; ++c) bn[c] = uniform_f(dde_b[c]) * (-LOG2E);

  f32x4 acc[4][4];   // [c][nt]
  #pragma unroll
  for (int c = 0; c < 4; ++c)
    #pragma unroll
    for (int nt = 0; nt < 4; ++nt) acc[c][nt] = (f32x4){0.f, 0.f, 0.f, 0.f};

  const _Float16* ap = qhh + ((size_t)(bh * L_SEQ + i0 + mr)) * HD + quad * 8;
  const _Float16* bp = khh + ((size_t)(bh * L_SEQ + j0 + mr)) * HD + quad * 8;

  #pragma unroll
  for (int ks = 0; ks < 2; ++ks) {
    uint4 qa = *(const uint4*)(ap + ks * 32);   // 2 atoms: [w|x][y|z][w'|x'][y'|z']
    unsigned s0 = ror16(qa.x), s1 = ror16(qa.y), s2 = ror16(qa.z), s3 = ror16(qa.w);
    u4h8 fr[4];
    // R0=(w,-x,-y,-z)  R1=(x,w,-z,y)  R2=(y,z,w,-x)  R3=(z,-y,x,w)
    fr[0].u = make_uint4(qa.x ^ 0x80000000u, qa.y ^ 0x80008000u,
                         qa.z ^ 0x80000000u, qa.w ^ 0x80008000u);
    fr[1].u = make_uint4(s0, s1 ^ 0x00008000u, s2, s3 ^ 0x00008000u);
    fr[2].u = make_uint4(qa.y, qa.x ^ 0x80000000u, qa.w, qa.z ^ 0x80000000u);
    fr[3].u = make_uint4(s1 ^ 0x80000000u, s0, s3 ^ 0x80000000u, s2);
    #pragma unroll
    for (int nt = 0; nt < 4; ++nt) {
      u4h8 bb; bb.h = *(const f16x8*)(bp + (size_t)nt * 16 * HD + ks * 32);
      #pragma unroll
      for (int c = 0; c < 4; ++c)
        acc[c][nt] = __builtin_amdgcn_mfma_f32_16x16x32_f16(fr[c].h, bb.h, acc[c][nt], 0, 0, 0);
    }
  }

  #pragma unroll
  for (int nt = 0; nt < 4; ++nt) {
    const int j = j0 + nt * 16 + mr;
    #pragma unroll
    for (int r = 0; r < 4; ++r) {
      const int i = i0 + quad * 4 + r;
      float S0 = acc[0][nt][r], S1 = acc[1][nt][r];
      float S2 = acc[2][nt][r], S3 = acc[3][nt][r];
      #pragma unroll
      for (int c = 0; c < 4; ++c) {
        float n = bn[c] + wn[c*4+0]*S0 + wn[c*4+1]*S1 + wn[c*4+2]*S2 + wn[c*4+3]*S3;
        float g = __builtin_amdgcn_rcpf(1.f + __builtin_amdgcn_exp2f(n));
        G[((size_t)(c * NBH + bh) * L_SEQ + i) * L_SEQ + j] = (_Float16)g;
      }
    }
  }
}

// ---------------------------------------------------------------------------
// pv_combine v2: wave w owns c=w (parallel across waves, was serial c-loop);
// i-strip shrunk 64->16 so grid = 24 x 4 x 16 = 1536 blocks (~24 waves/CU,
// was 1.5/SIMD -> latency-bound at 13% occupancy / 2.8% MfmaUtil).
// Wave: ACC_c = G_c[i-strip] @ Z0[cg-slice] (48 MFMA), apply signed qhat
// (sgn/tau packed-nibble masks, no runtime-indexed arrays), b-reduce via
// ds_swizzle XOR butterfly, deposit V_c[e] in LDS; one barrier; 256 threads
// compute ctx_d = sum_c V_c[c^d] and store bf16 CTXB directly.
// ---------------------------------------------------------------------------
__global__ __launch_bounds__(256) void pv_combine(
    const _Float16* __restrict__ G, const _Float16* __restrict__ Z0,
    const _Float16* __restrict__ qhh, unsigned short* __restrict__ CTXB)
{
  __shared__ float qs[16][17];          // qhat f32, +1 pad
  __shared__ float vxs[4][4][16][4];    // [c][e][il][nt]
  const int tid = threadIdx.x, c = tid >> 6, lane = tid & 63;
  const int mr = lane & 15, quad = lane >> 4;
  const int bh = blockIdx.z;
  const int i0 = blockIdx.x * 16;       // i-strip fastest: consecutive blocks share Z0
  const int cg = blockIdx.y;

  {  // stage qhat: 16 rows x 16 comps (this cg's 4 atoms)
    int il = tid >> 4, t = tid & 15;
    qs[il][t] = (float)qhh[((size_t)(bh * L_SEQ + i0 + il)) * HD + cg * 16 + t];
  }
  __syncthreads();

  const int bq = mr >> 2, e = mr & 3;
  // sgn_c(b) nibbles {E,4,8,2} -> 0x284E; tau(c,e) nibbles {0,A,6,C} -> 0xC6A0
  const unsigned msk =
      ((((0x284Eu >> (c * 4 + bq)) ^ (0xC6A0u >> (c * 4 + e))) & 1u) << 31);

  f32x4 acc[4];
  #pragma unroll
  for (int nt = 0; nt < 4; ++nt) acc[nt] = (f32x4){0.f, 0.f, 0.f, 0.f};

  const _Float16* apg = G +
      ((size_t)(c * NBH + bh) * L_SEQ + i0 + mr) * L_SEQ + quad * 8;
  const _Float16* bpz = Z0 + ((size_t)(bh * 256 + cg * 64 + mr)) * L_SEQ + quad * 8;

  #pragma unroll 4
  for (int k0 = 0; k0 < L_SEQ; k0 += 32) {
    u4h8 aa; aa.h = *(const f16x8*)(apg + k0);
    #pragma unroll
    for (int nt = 0; nt < 4; ++nt) {
      u4h8 bb; bb.h = *(const f16x8*)(bpz + (size_t)nt * 16 * L_SEQ + k0);
      acc[nt] = __builtin_amdgcn_mfma_f32_16x16x32_f16(aa.h, bb.h, acc[nt], 0, 0, 0);
    }
  }

  // signed-q multiply + b-reduce (lanes ^4, ^8), deposit V_c[e] per (il,nt)
  #pragma unroll
  for (int nt = 0; nt < 4; ++nt) {
    #pragma unroll
    for (int r = 0; r < 4; ++r) {
      int il = quad * 4 + r;
      float sq = __uint_as_float(__float_as_uint(qs[il][nt * 4 + (bq ^ c)]) ^ msk);
      float v = sq * acc[nt][r];
      v += swz_xor<0x101F>(v);
      v += swz_xor<0x201F>(v);
      if (bq == 0) vxs[c][e][il][nt] = v;
    }
  }
  __syncthreads();

  {  // final Klein combine: ctx_d = sum_c V_c[c^d]; 16x16 outputs
    int il = tid >> 4, cc = tid & 15, nt = cc >> 2, d = cc & 3;
    float s = vxs[0][d][il][nt] + vxs[1][1 ^ d][il][nt] +
              vxs[2][2 ^ d][il][nt] + vxs[3][3 ^ d][il][nt];
    int bb_ = bh >> 3, hh = bh & 7;
    CTXB[((size_t)(bb_ * L_SEQ + i0 + il)) * E_DIM + hh * HD + cg * 16 + nt * 4 + d] =
        (unsigned short)f2bf(s);
  }
}

// ---------------------------------------------------------------------------
// Workspace (max 24,117,248 B):
//   [0        ..   524288)  Wob bf16                       [whole run]
//   [524288   ..  1310720)  qhat f16                       [prep -> pv]
//   [1310720  ..  4456448)  Z0 f16                         [prep -> pv]
//   [4456448  ..  5242880)  khat f16 [prep->gate] | CTXB bf16 [pv->out]
//   [5242880  .. 24117248)  G f16 [gate -> pv]
//     overlays (dead before G written):
//     [5242880 ..  9961472)  Qw|Kw|Vw fp32                 [gemm -> prep]
//     [9961472 .. 12320768)  xb|Wqb|Wkb|Wvb bf16           [cvt -> gemm]
// ---------------------------------------------------------------------------
extern "C" void kernel_launch(void* const* d_in, const int* in_sizes, int n_in,
                              void* d_out, int out_size, void* d_ws, size_t ws_size,
                              hipStream_t stream)
{
  const float* x     = (const float*)d_in[0];
  const float* Wq    = (const float*)d_in[1];
  const float* Wk    = (const float*)d_in[2];
  const float* Wv    = (const float*)d_in[3];
  const float* Wo    = (const float*)d_in[4];
  const float* dde_w = (const float*)d_in[5];
  const float* dde_b = (const float*)d_in[6];
  float* out = (float*)d_out;

  char* ws = (char*)d_ws;
  unsigned short* Wob  = (unsigned short*)(ws + 0);
  _Float16* qhh = (_Float16*)(ws + 524288);
  _Float16* Z0h = (_Float16*)(ws + 1310720);
  _Float16* khh = (_Float16*)(ws + 4456448);
  unsigned short* CTXB = (unsigned short*)(ws + 4456448);
  _Float16* Gh  = (_Float16*)(ws + 5242880);
  float* Qw = (float*)(ws + 5242880);
  float* Kw = (float*)(ws + 6815744);
  float* Vw = (float*)(ws + 8388608);
  unsigned short* xb = (unsigned short*)(ws + 9961472);
  unsigned short* Wqb = (unsigned short*)(ws + 10747904);
  unsigned short* Wkb = (unsigned short*)(ws + 11272192);
  unsigned short* Wvb = (unsigned short*)(ws + 11796480);

  // 1) fp32 -> bf16 conversions
  to_bf16_all<<<1408, 256, 0, stream>>>(x, Wq, Wk, Wv, Wo, xb, Wob);

  // 2) Q/K/V projections: bf16 MFMA, head-scatter fp32 epilogue
  gemm_mfma<<<dim3(8, 12, 3), 256, 0, stream>>>(
      (const __bf16*)xb, (const __bf16*)Wqb, (const __bf16*)Wkb, (const __bf16*)Wvb,
      Qw, Kw, Vw, 2 * L_SEQ, E_DIM, E_DIM, 1);

  // 3) normalize + build qhat/khat f16 and shared PV operand Z0
  prep_norm_z<<<dim3(6, 4, 16), 256, 0, stream>>>(Qw, Kw, Vw, qhh, khh, Z0h);

  // 4) score GEMMs (in-register R_c fragments) + fused gate -> G f16
  score_gate<<<dim3(6, 6, 16), 256, 0, stream>>>(qhh, khh, dde_w, dde_b, Gh);

  // 5) PV GEMMs + LDS Klein combine -> CTXB bf16 (1536 blocks, wave=c)
  pv_combine<<<dim3(24, 4, 16), 256, 0, stream>>>(Gh, Z0h, qhh, CTXB);

  // 6) output projection: bf16 MFMA, fp32 out
  gemm_mfma<<<dim3(8, 12, 1), 256, 0, stream>>>(
      (const __bf16*)CTXB, (const __bf16*)Wob, nullptr, nullptr,
      out, nullptr, nullptr, 2 * L_SEQ, E_DIM, E_DIM, 0);
}

// Round 4
// 136.687 us; speedup vs baseline: 1.3236x; 1.2129x over previous
//
#include <hip/hip_runtime.h>
#include <math.h>

#define L_SEQ 384
#define E_DIM 512
#define NHEAD 8
#define NBH   16
#define HD    64
#define LOG2E 1.44269504f

typedef __attribute__((ext_vector_type(8))) __bf16 bf16x8;
typedef __attribute__((ext_vector_type(8))) _Float16 f16x8;
typedef __attribute__((ext_vector_type(4))) float f32x4;

union u4h8 { uint4 u; f16x8 h; };

__device__ __forceinline__ float uniform_f(float v) {
  return __uint_as_float(__builtin_amdgcn_readfirstlane(__float_as_uint(v)));
}

__device__ __forceinline__ unsigned f2bf(float f) {   // RNE float->bf16 bits
  unsigned u = __float_as_uint(f);
  return (u + 0x7FFFu + ((u >> 16) & 1u)) >> 16;
}

__device__ __forceinline__ unsigned ror16(unsigned x) { return (x >> 16) | (x << 16); }

template <int IMM>
__device__ __forceinline__ float swz_xor(float x) {   // ds_swizzle: imm must be literal
  return __int_as_float(__builtin_amdgcn_ds_swizzle(__float_as_int(x), IMM));
}

// Fragment-packed layout: a wave consumes one (16-row x 32-k) tile as
// lane(quad,mr) -> row=mr, k=quad*8..+7. Pack memory in exactly that order:
// [row/16][k/32][quad=(k>>3)&3][mr=row&15][e=k&7] -> coalesced 16B/lane loads.
__device__ __forceinline__ size_t pidx(int row, int k, int Kd) {
  return ((((size_t)(row >> 4) * (Kd >> 5) + (k >> 5)) * 4 + ((k >> 3) & 3)) * 16
          + (row & 15)) * 8 + (k & 7);
}

// ---------------------------------------------------------------------------
// Convert x|Wq|Wk|Wv (contiguous dst1) and Wo (dst2) to bf16, packed layout.
// Each thread: 4 consecutive k of one row -> one 8B store (k&7 in {0,4}).
// ---------------------------------------------------------------------------
__global__ __launch_bounds__(256) void to_bf16_all(
    const float* __restrict__ x, const float* __restrict__ Wq,
    const float* __restrict__ Wk, const float* __restrict__ Wv,
    const float* __restrict__ Wo, unsigned short* __restrict__ dst1,
    unsigned short* __restrict__ dst2)
{
  int e0 = (blockIdx.x * 256 + threadIdx.x) * 4;
  if (e0 >= 1441792) return;
  const float* src; unsigned short* d; int s;
  if (e0 < 393216)       { src = x;  s = e0;           d = dst1; }
  else if (e0 < 655360)  { src = Wq; s = e0 - 393216;  d = dst1 + 393216; }
  else if (e0 < 917504)  { src = Wk; s = e0 - 655360;  d = dst1 + 655360; }
  else if (e0 < 1179648) { src = Wv; s = e0 - 917504;  d = dst1 + 917504; }
  else                   { src = Wo; s = e0 - 1179648; d = dst2; }
  float4 v = *(const float4*)(src + s);
  unsigned lo = f2bf(v.x) | (f2bf(v.y) << 16);
  unsigned hi = f2bf(v.z) | (f2bf(v.w) << 16);
  int row = s >> 9, k = s & 511;
  *(uint2*)(d + pidx(row, k, 512)) = make_uint2(lo, hi);
}

// ---------------------------------------------------------------------------
// Pure-bf16 MFMA GEMM, packed-fragment operands. C = A @ B^T.
// Block 256 = 4 waves; tile 64x64; wave = 16-row strip, 4 n-tiles.
// mode 0: C[m*N+f]; mode 1: head-scatter C[((b*8+h)*L+l)*64+d].
// ---------------------------------------------------------------------------
__global__ __launch_bounds__(256) void gemm_mfma(
    const __bf16* __restrict__ A, const __bf16* __restrict__ B0,
    const __bf16* __restrict__ B1, const __bf16* __restrict__ B2,
    float* __restrict__ C0, float* __restrict__ C1, float* __restrict__ C2,
    int M, int N, int K, int mode)
{
  const int z = blockIdx.z;
  const __bf16* Bm = (z == 0) ? B0 : (z == 1) ? B1 : B2;
  float* Cp = (z == 0) ? C0 : (z == 1) ? C1 : C2;

  const int tid = threadIdx.x;
  const int wave = tid >> 6, lane = tid & 63;
  const int m0 = blockIdx.y * 64 + wave * 16;
  const int n0 = blockIdx.x * 64;
  const int mr = lane & 15, quad = lane >> 4;
  const int KT = K >> 5;

  f32x4 acc[4];
  #pragma unroll
  for (int nt = 0; nt < 4; ++nt) acc[nt] = (f32x4){0.f, 0.f, 0.f, 0.f};

  const __bf16* ap = A + (size_t)(m0 >> 4) * KT * 512 + lane * 8;
  const __bf16* bp = Bm + (size_t)(n0 >> 4) * KT * 512 + lane * 8;

  #pragma unroll 4
  for (int ks = 0; ks < KT; ++ks) {
    bf16x8 a = *(const bf16x8*)(ap + (size_t)ks * 512);
    #pragma unroll
    for (int nt = 0; nt < 4; ++nt) {
      bf16x8 b = *(const bf16x8*)(bp + ((size_t)nt * KT + ks) * 512);
      acc[nt] = __builtin_amdgcn_mfma_f32_16x16x32_bf16(a, b, acc[nt], 0, 0, 0);
    }
  }

  #pragma unroll
  for (int nt = 0; nt < 4; ++nt) {
    int n = n0 + nt * 16 + mr;
    #pragma unroll
    for (int r = 0; r < 4; ++r) {
      int m = m0 + quad * 4 + r;
      if (mode == 0) {
        Cp[(size_t)m * N + n] = acc[nt][r];
      } else {
        int b = m / L_SEQ, l = m % L_SEQ;
        int h = n >> 6, d = n & 63;
        Cp[((size_t)(b * NHEAD + h) * L_SEQ + l) * HD + d] = acc[nt][r];
      }
    }
  }
}

// ---------------------------------------------------------------------------
// prep_norm_z: per-atom normalize Q,K -> packed-f16 qhat/khat (Kd=64, global
// row = bh*L+l); build PV operand Z0[bh] packed (rows=col(a,b,e), Kd=384=j).
// grid (6 l-blocks, 4 a-groups, 16 bh) x 256.
// ---------------------------------------------------------------------------
__global__ __launch_bounds__(256) void prep_norm_z(
    const float* __restrict__ Qw, const float* __restrict__ Kw,
    const float* __restrict__ Vw, _Float16* __restrict__ qhh,
    _Float16* __restrict__ khh, _Float16* __restrict__ Z0)
{
  const int tid = threadIdx.x;
  const int l = blockIdx.x * 64 + (tid & 63);
  const int a = blockIdx.y * 4 + (tid >> 6);
  const int bh = blockIdx.z;
  const size_t base = ((size_t)(bh * L_SEQ + l)) * HD + a * 4;

  float4 qq = *(const float4*)(Qw + base);
  float dq = qq.x*qq.x + qq.y*qq.y + qq.z*qq.z + qq.w*qq.w;
  float rq = __builtin_amdgcn_rsqf(fmaxf(dq, 1e-30f));
  float4 kq = *(const float4*)(Kw + base);
  float dk = kq.x*kq.x + kq.y*kq.y + kq.z*kq.z + kq.w*kq.w;
  float rk = __builtin_amdgcn_rsqf(fmaxf(dk, 1e-30f));
  float4 vq = *(const float4*)(Vw + base);

  union { _Float16 h[4]; uint2 u; } pq, pk;
  pq.h[0] = (_Float16)(qq.x * rq); pq.h[1] = (_Float16)(qq.y * rq);
  pq.h[2] = (_Float16)(qq.z * rq); pq.h[3] = (_Float16)(qq.w * rq);
  float kb0 = kq.x * rk, kb1 = kq.y * rk, kb2 = kq.z * rk, kb3 = kq.w * rk;
  pk.h[0] = (_Float16)kb0; pk.h[1] = (_Float16)kb1;
  pk.h[2] = (_Float16)kb2; pk.h[3] = (_Float16)kb3;
  size_t qko = pidx(bh * L_SEQ + l, a * 4, 64);   // k&7 in {0,4}: 8B aligned
  *(uint2*)(qhh + qko) = pq.u;
  *(uint2*)(khh + qko) = pk.u;

  float kb[4] = {kb0, kb1, kb2, kb3};
  float ve[4] = {vq.x, vq.y, vq.z, vq.w};
  _Float16* zp = Z0 + (size_t)bh * (256 * 384);
  #pragma unroll
  for (int b = 0; b < 4; ++b)
    #pragma unroll
    for (int e = 0; e < 4; ++e)
      zp[pidx(a * 16 + b * 4 + e, l, 384)] = (_Float16)(kb[b] * ve[e]);
}

// ---------------------------------------------------------------------------
// score_gate: S_c[i,j] via MFMA (K=64, packed qhat/khat operands), gate
// G_c = sigmoid(...) -> packed-f16 G planes (rows=i, Kd=384=j) for pv A-use.
// grid (6 j-tiles, 6 i-tiles, 16 bh) x 256; tile 64x64; 32 MFMA/wave.
// ---------------------------------------------------------------------------
__global__ __launch_bounds__(256) void score_gate(
    const _Float16* __restrict__ qhh, const _Float16* __restrict__ khh,
    const float* __restrict__ dde_w, const float* __restrict__ dde_b,
    _Float16* __restrict__ G)
{
  const int tid = threadIdx.x, wave = tid >> 6, lane = tid & 63;
  const int mr = lane & 15, quad = lane >> 4;
  const int bh = blockIdx.z;
  const int i0 = blockIdx.y * 64 + wave * 16;
  const int j0 = blockIdx.x * 64;

  float wn[16], bn[4];
  #pragma unroll
  for (int t = 0; t < 16; ++t) wn[t] = uniform_f(dde_w[t]) * (-LOG2E * 0.0625f);
  #pragma unroll
  for (int c = 0; c < 4; ++c) bn[c] = uniform_f(dde_b[c]) * (-LOG2E);

  f32x4 acc[4][4];   // [c][nt]
  #pragma unroll
  for (int c = 0; c < 4; ++c)
    #pragma unroll
    for (int nt = 0; nt < 4; ++nt) acc[c][nt] = (f32x4){0.f, 0.f, 0.f, 0.f};

  const _Float16* ap = qhh + (size_t)((bh * L_SEQ + i0) >> 4) * 2 * 512 + lane * 8;
  const _Float16* bp = khh + (size_t)((bh * L_SEQ + j0) >> 4) * 2 * 512 + lane * 8;

  #pragma unroll
  for (int ks = 0; ks < 2; ++ks) {
    uint4 qa = *(const uint4*)(ap + ks * 512);  // 2 atoms: [w|x][y|z][w'|x'][y'|z']
    unsigned s0 = ror16(qa.x), s1 = ror16(qa.y), s2 = ror16(qa.z), s3 = ror16(qa.w);
    u4h8 fr[4];
    // R0=(w,-x,-y,-z)  R1=(x,w,-z,y)  R2=(y,z,w,-x)  R3=(z,-y,x,w)
    fr[0].u = make_uint4(qa.x ^ 0x80000000u, qa.y ^ 0x80008000u,
                         qa.z ^ 0x80000000u, qa.w ^ 0x80008000u);
    fr[1].u = make_uint4(s0, s1 ^ 0x00008000u, s2, s3 ^ 0x00008000u);
    fr[2].u = make_uint4(qa.y, qa.x ^ 0x80000000u, qa.w, qa.z ^ 0x80000000u);
    fr[3].u = make_uint4(s1 ^ 0x80000000u, s0, s3 ^ 0x80000000u, s2);
    #pragma unroll
    for (int nt = 0; nt < 4; ++nt) {
      u4h8 bb; bb.h = *(const f16x8*)(bp + ((size_t)nt * 2 + ks) * 512);
      #pragma unroll
      for (int c = 0; c < 4; ++c)
        acc[c][nt] = __builtin_amdgcn_mfma_f32_16x16x32_f16(fr[c].h, bb.h, acc[c][nt], 0, 0, 0);
    }
  }

  #pragma unroll
  for (int nt = 0; nt < 4; ++nt) {
    const int j = j0 + nt * 16 + mr;
    #pragma unroll
    for (int r = 0; r < 4; ++r) {
      const int i = i0 + quad * 4 + r;
      float S0 = acc[0][nt][r], S1 = acc[1][nt][r];
      float S2 = acc[2][nt][r], S3 = acc[3][nt][r];
      #pragma unroll
      for (int c = 0; c < 4; ++c) {
        float n = bn[c] + wn[c*4+0]*S0 + wn[c*4+1]*S1 + wn[c*4+2]*S2 + wn[c*4+3]*S3;
        float g = __builtin_amdgcn_rcpf(1.f + __builtin_amdgcn_exp2f(n));
        G[(size_t)(c * NBH + bh) * (384 * 384) + pidx(i, j, 384)] = (_Float16)g;
      }
    }
  }
}

// ---------------------------------------------------------------------------
// pv_combine v3: packed-fragment G (A) and Z0 (B) -> all loads coalesced
// 16B/lane. Wave w owns c=w; 48 MFMA; signed-qhat multiply; ds_swizzle
// b-reduce; LDS Klein combine; bf16 CTXB store in packed layout (Kd=512)
// for the final gemm's A-operand. grid (24 i-strips, 4 cg, 16 bh) x 256.
// ---------------------------------------------------------------------------
__global__ __launch_bounds__(256) void pv_combine(
    const _Float16* __restrict__ G, const _Float16* __restrict__ Z0,
    const _Float16* __restrict__ qhh, unsigned short* __restrict__ CTXB)
{
  __shared__ float qs[16][17];          // qhat f32, +1 pad
  __shared__ float vxs[4][4][16][4];    // [c][e][il][nt]
  const int tid = threadIdx.x, c = tid >> 6, lane = tid & 63;
  const int mr = lane & 15, quad = lane >> 4;
  const int bh = blockIdx.z;
  const int i0 = blockIdx.x * 16;       // i-strip fastest: consecutive blocks share Z0
  const int cg = blockIdx.y;

  {  // stage qhat: 16 rows x 16 comps (this cg's 4 atoms)
    int il = tid >> 4, t = tid & 15;
    qs[il][t] = (float)qhh[pidx(bh * L_SEQ + i0 + il, cg * 16 + t, 64)];
  }
  __syncthreads();

  const int bq = mr >> 2, e = mr & 3;
  // sgn_c(b) nibbles {E,4,8,2} -> 0x284E; tau(c,e) nibbles {0,A,6,C} -> 0xC6A0
  const unsigned msk =
      ((((0x284Eu >> (c * 4 + bq)) ^ (0xC6A0u >> (c * 4 + e))) & 1u) << 31);

  f32x4 acc[4];
  #pragma unroll
  for (int nt = 0; nt < 4; ++nt) acc[nt] = (f32x4){0.f, 0.f, 0.f, 0.f};

  const _Float16* apg = G + (size_t)(c * NBH + bh) * (384 * 384)
                          + (size_t)(i0 >> 4) * 12 * 512 + lane * 8;
  const _Float16* bpz = Z0 + (size_t)bh * (256 * 384)
                           + (size_t)(cg * 4) * 12 * 512 + lane * 8;

  #pragma unroll 4
  for (int ks = 0; ks < 12; ++ks) {
    u4h8 aa; aa.h = *(const f16x8*)(apg + (size_t)ks * 512);
    #pragma unroll
    for (int nt = 0; nt < 4; ++nt) {
      u4h8 bb; bb.h = *(const f16x8*)(bpz + ((size_t)nt * 12 + ks) * 512);
      acc[nt] = __builtin_amdgcn_mfma_f32_16x16x32_f16(aa.h, bb.h, acc[nt], 0, 0, 0);
    }
  }

  // signed-q multiply + b-reduce (lanes ^4, ^8), deposit V_c[e] per (il,nt)
  #pragma unroll
  for (int nt = 0; nt < 4; ++nt) {
    #pragma unroll
    for (int r = 0; r < 4; ++r) {
      int il = quad * 4 + r;
      float sq = __uint_as_float(__float_as_uint(qs[il][nt * 4 + (bq ^ c)]) ^ msk);
      float v = sq * acc[nt][r];
      v += swz_xor<0x101F>(v);
      v += swz_xor<0x201F>(v);
      if (bq == 0) vxs[c][e][il][nt] = v;
    }
  }
  __syncthreads();

  {  // final Klein combine: ctx_d = sum_c V_c[c^d]; 16x16 outputs (packed store)
    int il = tid >> 4, cc = tid & 15, nt = cc >> 2, d = cc & 3;
    float s = vxs[0][d][il][nt] + vxs[1][1 ^ d][il][nt] +
              vxs[2][2 ^ d][il][nt] + vxs[3][3 ^ d][il][nt];
    int bb_ = bh >> 3, hh = bh & 7;
    CTXB[pidx(bb_ * L_SEQ + i0 + il, hh * HD + cg * 16 + nt * 4 + d, 512)] =
        (unsigned short)f2bf(s);
  }
}

// ---------------------------------------------------------------------------
// Workspace (max 24,117,248 B):
//   [0        ..   524288)  Wob bf16 packed                [whole run]
//   [524288   ..  1310720)  qhat f16 packed                [prep -> pv]
//   [1310720  ..  4456448)  Z0 f16 packed                  [prep -> pv]
//   [4456448  ..  5242880)  khat f16 [prep->gate] | CTXB bf16 packed [pv->out]
//   [5242880  .. 24117248)  G f16 packed [gate -> pv]
//     overlays (dead before G written):
//     [5242880 ..  9961472)  Qw|Kw|Vw fp32                 [gemm -> prep]
//     [9961472 .. 12320768)  xb|Wqb|Wkb|Wvb bf16 packed    [cvt -> gemm]
// ---------------------------------------------------------------------------
extern "C" void kernel_launch(void* const* d_in, const int* in_sizes, int n_in,
                              void* d_out, int out_size, void* d_ws, size_t ws_size,
                              hipStream_t stream)
{
  const float* x     = (const float*)d_in[0];
  const float* Wq    = (const float*)d_in[1];
  const float* Wk    = (const float*)d_in[2];
  const float* Wv    = (const float*)d_in[3];
  const float* Wo    = (const float*)d_in[4];
  const float* dde_w = (const float*)d_in[5];
  const float* dde_b = (const float*)d_in[6];
  float* out = (float*)d_out;

  char* ws = (char*)d_ws;
  unsigned short* Wob  = (unsigned short*)(ws + 0);
  _Float16* qhh = (_Float16*)(ws + 524288);
  _Float16* Z0h = (_Float16*)(ws + 1310720);
  _Float16* khh = (_Float16*)(ws + 4456448);
  unsigned short* CTXB = (unsigned short*)(ws + 4456448);
  _Float16* Gh  = (_Float16*)(ws + 5242880);
  float* Qw = (float*)(ws + 5242880);
  float* Kw = (float*)(ws + 6815744);
  float* Vw = (float*)(ws + 8388608);
  unsigned short* xb = (unsigned short*)(ws + 9961472);
  unsigned short* Wqb = (unsigned short*)(ws + 10747904);
  unsigned short* Wkb = (unsigned short*)(ws + 11272192);
  unsigned short* Wvb = (unsigned short*)(ws + 11796480);

  // 1) fp32 -> bf16 conversions (packed-fragment layout)
  to_bf16_all<<<1408, 256, 0, stream>>>(x, Wq, Wk, Wv, Wo, xb, Wob);

  // 2) Q/K/V projections: bf16 MFMA, head-scatter fp32 epilogue
  gemm_mfma<<<dim3(8, 12, 3), 256, 0, stream>>>(
      (const __bf16*)xb, (const __bf16*)Wqb, (const __bf16*)Wkb, (const __bf16*)Wvb,
      Qw, Kw, Vw, 2 * L_SEQ, E_DIM, E_DIM, 1);

  // 3) normalize + build packed qhat/khat and PV operand Z0
  prep_norm_z<<<dim3(6, 4, 16), 256, 0, stream>>>(Qw, Kw, Vw, qhh, khh, Z0h);

  // 4) score GEMMs + fused gate -> packed G
  score_gate<<<dim3(6, 6, 16), 256, 0, stream>>>(qhh, khh, dde_w, dde_b, Gh);

  // 5) PV GEMMs + LDS Klein combine -> packed CTXB bf16
  pv_combine<<<dim3(24, 4, 16), 256, 0, stream>>>(Gh, Z0h, qhh, CTXB);

  // 6) output projection: bf16 MFMA, fp32 out
  gemm_mfma<<<dim3(8, 12, 1), 256, 0, stream>>>(
      (const __bf16*)CTXB, (const __bf16*)Wob, nullptr, nullptr,
      out, nullptr, nullptr, 2 * L_SEQ, E_DIM, E_DIM, 0);
}

// Round 5
// 112.165 us; speedup vs baseline: 1.6129x; 1.2186x over previous
//
#include <hip/hip_runtime.h>
#include <math.h>

#define L_SEQ 384
#define E_DIM 512
#define NHEAD 8
#define NBH   16
#define HD    64
#define LOG2E 1.44269504f

typedef __attribute__((ext_vector_type(8))) __bf16 bf16x8;
typedef __attribute__((ext_vector_type(8))) _Float16 f16x8;
typedef __attribute__((ext_vector_type(4))) float f32x4;

union u4h8 { uint4 u; f16x8 h; };

__device__ __forceinline__ float uniform_f(float v) {
  return __uint_as_float(__builtin_amdgcn_readfirstlane(__float_as_uint(v)));
}

__device__ __forceinline__ unsigned f2bf(float f) {   // RNE float->bf16 bits
  unsigned u = __float_as_uint(f);
  return (u + 0x7FFFu + ((u >> 16) & 1u)) >> 16;
}

__device__ __forceinline__ unsigned ror16(unsigned x) { return (x >> 16) | (x << 16); }

// quad_perm DPP: sum over the 4 lanes of each aligned 4-lane group
__device__ __forceinline__ float dpp_xor1(float x) {
  return __int_as_float(__builtin_amdgcn_mov_dpp(__float_as_int(x), 0xB1, 0xF, 0xF, 0));
}
__device__ __forceinline__ float dpp_xor2(float x) {
  return __int_as_float(__builtin_amdgcn_mov_dpp(__float_as_int(x), 0x4E, 0xF, 0xF, 0));
}
template <int IMM>
__device__ __forceinline__ float swz_xor(float x) {   // ds_swizzle: imm must be literal
  return __int_as_float(__builtin_amdgcn_ds_swizzle(__float_as_int(x), IMM));
}

// Fragment-packed layout: a wave consumes one (16-row x 32-k) tile as
// lane(quad,mr) -> row=mr, k=quad*8..+7. Pack memory in exactly that order:
// [row/16][k/32][quad=(k>>3)&3][mr=row&15][e=k&7] -> coalesced 16B/lane loads.
__device__ __forceinline__ size_t pidx(int row, int k, int Kd) {
  return ((((size_t)(row >> 4) * (Kd >> 5) + (k >> 5)) * 4 + ((k >> 3) & 3)) * 16
          + (row & 15)) * 8 + (k & 7);
}

// ---------------------------------------------------------------------------
// Convert x|Wq|Wk|Wv (dst1) and Wo (dst2) to bf16 packed; also zero `out`
// (needed by the K-split atomic out-gemm; this kernel runs first).
// ---------------------------------------------------------------------------
__global__ __launch_bounds__(256) void to_bf16_all(
    const float* __restrict__ x, const float* __restrict__ Wq,
    const float* __restrict__ Wk, const float* __restrict__ Wv,
    const float* __restrict__ Wo, unsigned short* __restrict__ dst1,
    unsigned short* __restrict__ dst2, float* __restrict__ outz)
{
  int e0 = (blockIdx.x * 256 + threadIdx.x) * 4;
  if (e0 >= 1835008) return;
  if (e0 >= 1441792) {                       // zero the output buffer
    *(float4*)(outz + (e0 - 1441792)) = make_float4(0.f, 0.f, 0.f, 0.f);
    return;
  }
  const float* src; unsigned short* d; int s;
  if (e0 < 393216)       { src = x;  s = e0;           d = dst1; }
  else if (e0 < 655360)  { src = Wq; s = e0 - 393216;  d = dst1 + 393216; }
  else if (e0 < 917504)  { src = Wk; s = e0 - 655360;  d = dst1 + 655360; }
  else if (e0 < 1179648) { src = Wv; s = e0 - 917504;  d = dst1 + 917504; }
  else                   { src = Wo; s = e0 - 1179648; d = dst2; }
  float4 v = *(const float4*)(src + s);
  unsigned lo = f2bf(v.x) | (f2bf(v.y) << 16);
  unsigned hi = f2bf(v.z) | (f2bf(v.w) << 16);
  int row = s >> 9, k = s & 511;
  *(uint2*)(d + pidx(row, k, 512)) = make_uint2(lo, hi);
}

// ---------------------------------------------------------------------------
// bf16 MFMA GEMM, packed-fragment operands. C = A @ B^T. tile 64m x (16*NTN)n.
// MODE 1 (QKV): z selects B/C; epilogue does per-atom quaternion normalize
//   (DPP quad-sum across the 4 lanes holding d..d+3) for z<2, then packed-f16
//   store (row=(b*8+h)*L+l, k=d, Kd=64). Eliminates the fp32 Q/K/V round-trip.
// MODE 2 (out): z = K-split chunk (128 wide); f32 atomic-add epilogue.
// ---------------------------------------------------------------------------
template <int NTN, int MODE>
__global__ __launch_bounds__(256) void gemm_mfma(
    const __bf16* __restrict__ A, const __bf16* __restrict__ B0,
    const __bf16* __restrict__ B1, const __bf16* __restrict__ B2,
    float* __restrict__ C0, float* __restrict__ C1, float* __restrict__ C2,
    int M, int N, int K)
{
  const int z = blockIdx.z;
  const __bf16* Bm = (MODE == 2) ? B0 : (z == 0) ? B0 : (z == 1) ? B1 : B2;
  float* Cp = (MODE == 2) ? C0 : (z == 0) ? C0 : (z == 1) ? C1 : C2;

  const int tid = threadIdx.x;
  const int wave = tid >> 6, lane = tid & 63;
  const int m0 = blockIdx.y * 64 + wave * 16;
  const int n0 = blockIdx.x * (16 * NTN);
  const int mr = lane & 15, quad = lane >> 4;
  const int KT = K >> 5;
  const int kb0 = (MODE == 2) ? z * 4 : 0;   // K-split start (32-blocks)
  const int KL = (MODE == 2) ? 4 : KT;

  f32x4 acc[NTN];
  #pragma unroll
  for (int nt = 0; nt < NTN; ++nt) acc[nt] = (f32x4){0.f, 0.f, 0.f, 0.f};

  const __bf16* ap = A + ((size_t)(m0 >> 4) * KT + kb0) * 512 + lane * 8;
  const __bf16* bp = Bm + ((size_t)(n0 >> 4) * KT + kb0) * 512 + lane * 8;

  #pragma unroll 4
  for (int ks = 0; ks < KL; ++ks) {
    bf16x8 a = *(const bf16x8*)(ap + (size_t)ks * 512);
    #pragma unroll
    for (int nt = 0; nt < NTN; ++nt) {
      bf16x8 b = *(const bf16x8*)(bp + ((size_t)nt * KT + ks) * 512);
      acc[nt] = __builtin_amdgcn_mfma_f32_16x16x32_bf16(a, b, acc[nt], 0, 0, 0);
    }
  }

  if (MODE == 2) {
    #pragma unroll
    for (int nt = 0; nt < NTN; ++nt) {
      int n = n0 + nt * 16 + mr;
      #pragma unroll
      for (int r = 0; r < 4; ++r) {
        int m = m0 + quad * 4 + r;
        __hip_atomic_fetch_add(&Cp[(size_t)m * N + n], acc[nt][r],
                               __ATOMIC_RELAXED, __HIP_MEMORY_SCOPE_AGENT);
      }
    }
  } else {
    _Float16* Hp = (_Float16*)Cp;
    #pragma unroll
    for (int nt = 0; nt < NTN; ++nt) {
      int n = n0 + nt * 16 + mr;
      #pragma unroll
      for (int r = 0; r < 4; ++r) {
        float val = acc[nt][r];
        float s = val * val;
        s += dpp_xor1(s);
        s += dpp_xor2(s);          // s = |atom|^2 across the 4 component lanes
        float sc = (z == 2) ? 1.f : __builtin_amdgcn_rsqf(fmaxf(s, 1e-30f));
        int m = m0 + quad * 4 + r;
        int b = m / L_SEQ, l = m - b * L_SEQ;
        int row = (b * NHEAD + (n >> 6)) * L_SEQ + l;
        Hp[pidx(row, n & 63, 64)] = (_Float16)(val * sc);
      }
    }
  }
}

// ---------------------------------------------------------------------------
// z_build: Z0[bh][col=(a,b,e)][j] = khat_b(j,a) * v_e(j,a), packed f16.
// Reads only 1.6 MB of f16 (khat/vhat) -- fp32 staging eliminated.
// grid (6 j-blocks, 4 a-groups, 16 bh) x 256.
// ---------------------------------------------------------------------------
__global__ __launch_bounds__(256) void z_build(
    const _Float16* __restrict__ khh, const _Float16* __restrict__ vhh,
    _Float16* __restrict__ Z0)
{
  const int tid = threadIdx.x;
  const int l = blockIdx.x * 64 + (tid & 63);
  const int a = blockIdx.y * 4 + (tid >> 6);
  const int bh = blockIdx.z;

  size_t off = pidx(bh * L_SEQ + l, a * 4, 64);  // a*4 % 8 in {0,4}: 8B aligned
  union { uint2 u; _Float16 h[4]; } kk, vv;
  kk.u = *(const uint2*)(khh + off);
  vv.u = *(const uint2*)(vhh + off);

  float kb[4] = {(float)kk.h[0], (float)kk.h[1], (float)kk.h[2], (float)kk.h[3]};
  float ve[4] = {(float)vv.h[0], (float)vv.h[1], (float)vv.h[2], (float)vv.h[3]};
  _Float16* zp = Z0 + (size_t)bh * (256 * 384);
  #pragma unroll
  for (int b = 0; b < 4; ++b)
    #pragma unroll
    for (int e = 0; e < 4; ++e)
      zp[pidx(a * 16 + b * 4 + e, l, 384)] = (_Float16)(kb[b] * ve[e]);
}

// ---------------------------------------------------------------------------
// score_gate: S_c[i,j] via MFMA (K=64, packed operands), fused sigmoid gate
// -> packed-f16 G planes (rows=i, Kd=384=j). j-tile 32 -> grid
// (12 j, 6 i, 16 bh) = 1152 blocks (4.5/CU). 16 MFMA/wave.
// ---------------------------------------------------------------------------
__global__ __launch_bounds__(256) void score_gate(
    const _Float16* __restrict__ qhh, const _Float16* __restrict__ khh,
    const float* __restrict__ dde_w, const float* __restrict__ dde_b,
    _Float16* __restrict__ G)
{
  const int tid = threadIdx.x, wave = tid >> 6, lane = tid & 63;
  const int mr = lane & 15, quad = lane >> 4;
  const int bh = blockIdx.z;
  const int i0 = blockIdx.y * 64 + wave * 16;
  const int j0 = blockIdx.x * 32;

  float wn[16], bn[4];
  #pragma unroll
  for (int t = 0; t < 16; ++t) wn[t] = uniform_f(dde_w[t]) * (-LOG2E * 0.0625f);
  #pragma unroll
  for (int c = 0; c < 4; ++c) bn[c] = uniform_f(dde_b[c]) * (-LOG2E);

  f32x4 acc[4][2];   // [c][nt]
  #pragma unroll
  for (int c = 0; c < 4; ++c)
    #pragma unroll
    for (int nt = 0; nt < 2; ++nt) acc[c][nt] = (f32x4){0.f, 0.f, 0.f, 0.f};

  const _Float16* ap = qhh + (size_t)((bh * L_SEQ + i0) >> 4) * 2 * 512 + lane * 8;
  const _Float16* bp = khh + (size_t)((bh * L_SEQ + j0) >> 4) * 2 * 512 + lane * 8;

  #pragma unroll
  for (int ks = 0; ks < 2; ++ks) {
    uint4 qa = *(const uint4*)(ap + ks * 512);  // 2 atoms: [w|x][y|z][w'|x'][y'|z']
    unsigned s0 = ror16(qa.x), s1 = ror16(qa.y), s2 = ror16(qa.z), s3 = ror16(qa.w);
    u4h8 fr[4];
    // R0=(w,-x,-y,-z)  R1=(x,w,-z,y)  R2=(y,z,w,-x)  R3=(z,-y,x,w)
    fr[0].u = make_uint4(qa.x ^ 0x80000000u, qa.y ^ 0x80008000u,
                         qa.z ^ 0x80000000u, qa.w ^ 0x80008000u);
    fr[1].u = make_uint4(s0, s1 ^ 0x00008000u, s2, s3 ^ 0x00008000u);
    fr[2].u = make_uint4(qa.y, qa.x ^ 0x80000000u, qa.w, qa.z ^ 0x80000000u);
    fr[3].u = make_uint4(s1 ^ 0x80000000u, s0, s3 ^ 0x80000000u, s2);
    #pragma unroll
    for (int nt = 0; nt < 2; ++nt) {
      u4h8 bb; bb.h = *(const f16x8*)(bp + ((size_t)nt * 2 + ks) * 512);
      #pragma unroll
      for (int c = 0; c < 4; ++c)
        acc[c][nt] = __builtin_amdgcn_mfma_f32_16x16x32_f16(fr[c].h, bb.h, acc[c][nt], 0, 0, 0);
    }
  }

  #pragma unroll
  for (int nt = 0; nt < 2; ++nt) {
    const int j = j0 + nt * 16 + mr;
    #pragma unroll
    for (int r = 0; r < 4; ++r) {
      const int i = i0 + quad * 4 + r;
      float S0 = acc[0][nt][r], S1 = acc[1][nt][r];
      float S2 = acc[2][nt][r], S3 = acc[3][nt][r];
      #pragma unroll
      for (int c = 0; c < 4; ++c) {
        float n = bn[c] + wn[c*4+0]*S0 + wn[c*4+1]*S1 + wn[c*4+2]*S2 + wn[c*4+3]*S3;
        float g = __builtin_amdgcn_rcpf(1.f + __builtin_amdgcn_exp2f(n));
        G[(size_t)(c * NBH + bh) * (384 * 384) + pidx(i, j, 384)] = (_Float16)g;
      }
    }
  }
}

// ---------------------------------------------------------------------------
// pv_combine: packed G (A) and Z0 (B), all loads coalesced 16B/lane.
// Wave w owns c=w; 48 MFMA; signed-qhat multiply; ds_swizzle b-reduce; LDS
// Klein combine; packed bf16 CTXB store. grid (24, 4, 16) = 1536 blocks.
// ---------------------------------------------------------------------------
__global__ __launch_bounds__(256) void pv_combine(
    const _Float16* __restrict__ G, const _Float16* __restrict__ Z0,
    const _Float16* __restrict__ qhh, unsigned short* __restrict__ CTXB)
{
  __shared__ float qs[16][17];          // qhat f32, +1 pad
  __shared__ float vxs[4][4][16][4];    // [c][e][il][nt]
  const int tid = threadIdx.x, c = tid >> 6, lane = tid & 63;
  const int mr = lane & 15, quad = lane >> 4;
  const int bh = blockIdx.z;
  const int i0 = blockIdx.x * 16;       // i-strip fastest: consecutive blocks share Z0
  const int cg = blockIdx.y;

  {  // stage qhat: 16 rows x 16 comps (this cg's 4 atoms)
    int il = tid >> 4, t = tid & 15;
    qs[il][t] = (float)qhh[pidx(bh * L_SEQ + i0 + il, cg * 16 + t, 64)];
  }
  __syncthreads();

  const int bq = mr >> 2, e = mr & 3;
  // sgn_c(b) nibbles {E,4,8,2} -> 0x284E; tau(c,e) nibbles {0,A,6,C} -> 0xC6A0
  const unsigned msk =
      ((((0x284Eu >> (c * 4 + bq)) ^ (0xC6A0u >> (c * 4 + e))) & 1u) << 31);

  f32x4 acc[4];
  #pragma unroll
  for (int nt = 0; nt < 4; ++nt) acc[nt] = (f32x4){0.f, 0.f, 0.f, 0.f};

  const _Float16* apg = G + (size_t)(c * NBH + bh) * (384 * 384)
                          + (size_t)(i0 >> 4) * 12 * 512 + lane * 8;
  const _Float16* bpz = Z0 + (size_t)bh * (256 * 384)
                           + (size_t)(cg * 4) * 12 * 512 + lane * 8;

  #pragma unroll 4
  for (int ks = 0; ks < 12; ++ks) {
    u4h8 aa; aa.h = *(const f16x8*)(apg + (size_t)ks * 512);
    #pragma unroll
    for (int nt = 0; nt < 4; ++nt) {
      u4h8 bb; bb.h = *(const f16x8*)(bpz + ((size_t)nt * 12 + ks) * 512);
      acc[nt] = __builtin_amdgcn_mfma_f32_16x16x32_f16(aa.h, bb.h, acc[nt], 0, 0, 0);
    }
  }

  // signed-q multiply + b-reduce (lanes ^4, ^8), deposit V_c[e] per (il,nt)
  #pragma unroll
  for (int nt = 0; nt < 4; ++nt) {
    #pragma unroll
    for (int r = 0; r < 4; ++r) {
      int il = quad * 4 + r;
      float sq = __uint_as_float(__float_as_uint(qs[il][nt * 4 + (bq ^ c)]) ^ msk);
      float v = sq * acc[nt][r];
      v += swz_xor<0x101F>(v);
      v += swz_xor<0x201F>(v);
      if (bq == 0) vxs[c][e][il][nt] = v;
    }
  }
  __syncthreads();

  {  // final Klein combine: ctx_d = sum_c V_c[c^d]; 16x16 outputs (packed store)
    int il = tid >> 4, cc = tid & 15, nt = cc >> 2, d = cc & 3;
    float s = vxs[0][d][il][nt] + vxs[1][1 ^ d][il][nt] +
              vxs[2][2 ^ d][il][nt] + vxs[3][3 ^ d][il][nt];
    int bb_ = bh >> 3, hh = bh & 7;
    CTXB[pidx(bb_ * L_SEQ + i0 + il, hh * HD + cg * 16 + nt * 4 + d, 512)] =
        (unsigned short)f2bf(s);
  }
}

// ---------------------------------------------------------------------------
// Workspace (24,117,248 B):
//   [0        ..   524288)  Wob bf16 packed                [whole run]
//   [524288   ..  1310720)  qhat f16 packed                [gemm -> pv]
//   [1310720  ..  2097152)  khat f16 packed [gemm -> score] | CTXB [pv -> out]
//   [2097152  ..  5242880)  Z0 f16 packed                  [z_build -> pv]
//   [5242880  .. 24117248)  G f16 packed                   [score -> pv]
//     overlays (dead before G written):
//     [5242880 ..  6029312)  vhat f16 packed               [gemm -> z_build]
//     [6029312 ..  8388608)  xb|Wqb|Wkb|Wvb bf16 packed    [cvt -> gemm]
// ---------------------------------------------------------------------------
extern "C" void kernel_launch(void* const* d_in, const int* in_sizes, int n_in,
                              void* d_out, int out_size, void* d_ws, size_t ws_size,
                              hipStream_t stream)
{
  const float* x     = (const float*)d_in[0];
  const float* Wq    = (const float*)d_in[1];
  const float* Wk    = (const float*)d_in[2];
  const float* Wv    = (const float*)d_in[3];
  const float* Wo    = (const float*)d_in[4];
  const float* dde_w = (const float*)d_in[5];
  const float* dde_b = (const float*)d_in[6];
  float* out = (float*)d_out;

  char* ws = (char*)d_ws;
  unsigned short* Wob  = (unsigned short*)(ws + 0);
  _Float16* qhh = (_Float16*)(ws + 524288);
  _Float16* khh = (_Float16*)(ws + 1310720);
  unsigned short* CTXB = (unsigned short*)(ws + 1310720);
  _Float16* Z0h = (_Float16*)(ws + 2097152);
  _Float16* Gh  = (_Float16*)(ws + 5242880);
  _Float16* vhh = (_Float16*)(ws + 5242880);
  unsigned short* xb  = (unsigned short*)(ws + 6029312);
  unsigned short* Wqb = (unsigned short*)(ws + 6815744);
  unsigned short* Wkb = (unsigned short*)(ws + 7340032);
  unsigned short* Wvb = (unsigned short*)(ws + 7864320);

  // 1) fp32 -> bf16 conversions (packed) + zero `out`
  to_bf16_all<<<1792, 256, 0, stream>>>(x, Wq, Wk, Wv, Wo, xb, Wob, out);

  // 2) Q/K/V projections + fused per-atom normalize -> packed f16 qhat/khat/vhat
  gemm_mfma<2, 1><<<dim3(16, 12, 3), 256, 0, stream>>>(
      (const __bf16*)xb, (const __bf16*)Wqb, (const __bf16*)Wkb, (const __bf16*)Wvb,
      (float*)qhh, (float*)khh, (float*)vhh, 2 * L_SEQ, E_DIM, E_DIM);

  // 3) PV operand Z0 = khat_b * v_e (reads 1.6 MB f16)
  z_build<<<dim3(6, 4, 16), 256, 0, stream>>>(khh, vhh, Z0h);

  // 4) score GEMMs + fused gate -> packed G (1152 blocks)
  score_gate<<<dim3(12, 6, 16), 256, 0, stream>>>(qhh, khh, dde_w, dde_b, Gh);

  // 5) PV GEMMs + LDS Klein combine -> packed CTXB bf16
  pv_combine<<<dim3(24, 4, 16), 256, 0, stream>>>(Gh, Z0h, qhh, CTXB);

  // 6) output projection: K-split x4, f32 atomic-add (768 blocks)
  gemm_mfma<2, 2><<<dim3(16, 12, 4), 256, 0, stream>>>(
      (const __bf16*)CTXB, (const __bf16*)Wob, nullptr, nullptr,
      out, nullptr, nullptr, 2 * L_SEQ, E_DIM, E_DIM);
}

// Round 6
// 110.062 us; speedup vs baseline: 1.6437x; 1.0191x over previous
//
#include <hip/hip_runtime.h>
#include <math.h>

#define L_SEQ 384
#define E_DIM 512
#define NHEAD 8
#define NBH   16
#define HD    64
#define LOG2E 1.44269504f

typedef __attribute__((ext_vector_type(8))) __bf16 bf16x8;
typedef __attribute__((ext_vector_type(8))) _Float16 f16x8;
typedef __attribute__((ext_vector_type(4))) float f32x4;

union u4h8 { uint4 u; f16x8 h; };

__device__ __forceinline__ float uniform_f(float v) {
  return __uint_as_float(__builtin_amdgcn_readfirstlane(__float_as_uint(v)));
}

__device__ __forceinline__ unsigned f2bf(float f) {   // RNE float->bf16 bits
  unsigned u = __float_as_uint(f);
  return (u + 0x7FFFu + ((u >> 16) & 1u)) >> 16;
}

__device__ __forceinline__ unsigned ror16(unsigned x) { return (x >> 16) | (x << 16); }

// quad_perm DPP: butterfly over the 4 lanes of each aligned 4-lane group
__device__ __forceinline__ float dpp_xor1(float x) {
  return __int_as_float(__builtin_amdgcn_mov_dpp(__float_as_int(x), 0xB1, 0xF, 0xF, 0));
}
__device__ __forceinline__ float dpp_xor2(float x) {
  return __int_as_float(__builtin_amdgcn_mov_dpp(__float_as_int(x), 0x4E, 0xF, 0xF, 0));
}
template <int IMM>
__device__ __forceinline__ float swz_xor(float x) {   // ds_swizzle: imm must be literal
  return __int_as_float(__builtin_amdgcn_ds_swizzle(__float_as_int(x), IMM));
}

// Fragment-packed layout: a wave consumes one (16-row x 32-k) tile as
// lane(quad,mr) -> row=mr, k=quad*8..+7. Pack memory in exactly that order:
// [row/16][k/32][quad=(k>>3)&3][mr=row&15][e=k&7] -> coalesced 16B/lane loads.
__device__ __forceinline__ size_t pidx(int row, int k, int Kd) {
  return ((((size_t)(row >> 4) * (Kd >> 5) + (k >> 5)) * 4 + ((k >> 3) & 3)) * 16
          + (row & 15)) * 8 + (k & 7);
}

// ---------------------------------------------------------------------------
// Convert x|Wq|Wk|Wv (dst1) and Wo (dst2) to bf16 packed; also zero `out`
// (needed by the K-split atomic out-gemm; this kernel runs first).
// ---------------------------------------------------------------------------
__global__ __launch_bounds__(256) void to_bf16_all(
    const float* __restrict__ x, const float* __restrict__ Wq,
    const float* __restrict__ Wk, const float* __restrict__ Wv,
    const float* __restrict__ Wo, unsigned short* __restrict__ dst1,
    unsigned short* __restrict__ dst2, float* __restrict__ outz)
{
  int e0 = (blockIdx.x * 256 + threadIdx.x) * 4;
  if (e0 >= 1835008) return;
  if (e0 >= 1441792) {                       // zero the output buffer
    *(float4*)(outz + (e0 - 1441792)) = make_float4(0.f, 0.f, 0.f, 0.f);
    return;
  }
  const float* src; unsigned short* d; int s;
  if (e0 < 393216)       { src = x;  s = e0;           d = dst1; }
  else if (e0 < 655360)  { src = Wq; s = e0 - 393216;  d = dst1 + 393216; }
  else if (e0 < 917504)  { src = Wk; s = e0 - 655360;  d = dst1 + 655360; }
  else if (e0 < 1179648) { src = Wv; s = e0 - 917504;  d = dst1 + 917504; }
  else                   { src = Wo; s = e0 - 1179648; d = dst2; }
  float4 v = *(const float4*)(src + s);
  unsigned lo = f2bf(v.x) | (f2bf(v.y) << 16);
  unsigned hi = f2bf(v.z) | (f2bf(v.w) << 16);
  int row = s >> 9, k = s & 511;
  *(uint2*)(d + pidx(row, k, 512)) = make_uint2(lo, hi);
}

// ---------------------------------------------------------------------------
// bf16 MFMA GEMM, packed-fragment operands. C = A @ B^T. tile 64m x (16*NTN)n.
// MODE 1 (QKV): z selects B/C; epilogue does per-atom quaternion normalize
//   (DPP quad-sum across the 4 lanes holding d..d+3) for z<2, then packed-f16
//   store (row=(b*8+h)*L+l, k=d, Kd=64).
// MODE 2 (out): z = K-split chunk (128 wide); f32 atomic-add epilogue.
// ---------------------------------------------------------------------------
template <int NTN, int MODE>
__global__ __launch_bounds__(256) void gemm_mfma(
    const __bf16* __restrict__ A, const __bf16* __restrict__ B0,
    const __bf16* __restrict__ B1, const __bf16* __restrict__ B2,
    float* __restrict__ C0, float* __restrict__ C1, float* __restrict__ C2,
    int M, int N, int K)
{
  const int z = blockIdx.z;
  const __bf16* Bm = (MODE == 2) ? B0 : (z == 0) ? B0 : (z == 1) ? B1 : B2;
  float* Cp = (MODE == 2) ? C0 : (z == 0) ? C0 : (z == 1) ? C1 : C2;

  const int tid = threadIdx.x;
  const int wave = tid >> 6, lane = tid & 63;
  const int m0 = blockIdx.y * 64 + wave * 16;
  const int n0 = blockIdx.x * (16 * NTN);
  const int mr = lane & 15, quad = lane >> 4;
  const int KT = K >> 5;
  const int kb0 = (MODE == 2) ? z * 4 : 0;   // K-split start (32-blocks)
  const int KL = (MODE == 2) ? 4 : KT;

  f32x4 acc[NTN];
  #pragma unroll
  for (int nt = 0; nt < NTN; ++nt) acc[nt] = (f32x4){0.f, 0.f, 0.f, 0.f};

  const __bf16* ap = A + ((size_t)(m0 >> 4) * KT + kb0) * 512 + lane * 8;
  const __bf16* bp = Bm + ((size_t)(n0 >> 4) * KT + kb0) * 512 + lane * 8;

  #pragma unroll 4
  for (int ks = 0; ks < KL; ++ks) {
    bf16x8 a = *(const bf16x8*)(ap + (size_t)ks * 512);
    #pragma unroll
    for (int nt = 0; nt < NTN; ++nt) {
      bf16x8 b = *(const bf16x8*)(bp + ((size_t)nt * KT + ks) * 512);
      acc[nt] = __builtin_amdgcn_mfma_f32_16x16x32_bf16(a, b, acc[nt], 0, 0, 0);
    }
  }

  if (MODE == 2) {
    #pragma unroll
    for (int nt = 0; nt < NTN; ++nt) {
      int n = n0 + nt * 16 + mr;
      #pragma unroll
      for (int r = 0; r < 4; ++r) {
        int m = m0 + quad * 4 + r;
        __hip_atomic_fetch_add(&Cp[(size_t)m * N + n], acc[nt][r],
                               __ATOMIC_RELAXED, __HIP_MEMORY_SCOPE_AGENT);
      }
    }
  } else {
    _Float16* Hp = (_Float16*)Cp;
    #pragma unroll
    for (int nt = 0; nt < NTN; ++nt) {
      int n = n0 + nt * 16 + mr;
      #pragma unroll
      for (int r = 0; r < 4; ++r) {
        float val = acc[nt][r];
        float s = val * val;
        s += dpp_xor1(s);
        s += dpp_xor2(s);          // |atom|^2 across the 4 component lanes
        float sc = (z == 2) ? 1.f : __builtin_amdgcn_rsqf(fmaxf(s, 1e-30f));
        int m = m0 + quad * 4 + r;
        int b = m / L_SEQ, l = m - b * L_SEQ;
        int row = (b * NHEAD + (n >> 6)) * L_SEQ + l;
        Hp[pidx(row, n & 63, 64)] = (_Float16)(val * sc);
      }
    }
  }
}

// ---------------------------------------------------------------------------
// z_build: Z0[bh][col=(a,b,e)][j] = khat_b(j,a) * v_e(j,a), packed f16.
// grid (6 j-blocks, 4 a-groups, 16 bh) x 256.
// ---------------------------------------------------------------------------
__global__ __launch_bounds__(256) void z_build(
    const _Float16* __restrict__ khh, const _Float16* __restrict__ vhh,
    _Float16* __restrict__ Z0)
{
  const int tid = threadIdx.x;
  const int l = blockIdx.x * 64 + (tid & 63);
  const int a = blockIdx.y * 4 + (tid >> 6);
  const int bh = blockIdx.z;

  size_t off = pidx(bh * L_SEQ + l, a * 4, 64);
  union { uint2 u; _Float16 h[4]; } kk, vv;
  kk.u = *(const uint2*)(khh + off);
  vv.u = *(const uint2*)(vhh + off);

  float kb[4] = {(float)kk.h[0], (float)kk.h[1], (float)kk.h[2], (float)kk.h[3]};
  float ve[4] = {(float)vv.h[0], (float)vv.h[1], (float)vv.h[2], (float)vv.h[3]};
  _Float16* zp = Z0 + (size_t)bh * (256 * 384);
  #pragma unroll
  for (int b = 0; b < 4; ++b)
    #pragma unroll
    for (int e = 0; e < 4; ++e)
      zp[pidx(a * 16 + b * 4 + e, l, 384)] = (_Float16)(kb[b] * ve[e]);
}

// ---------------------------------------------------------------------------
// gate_pv: FUSED score -> gate -> PV. Eliminates the 18.9 MB G tensor
// (was: scattered global write + 4x re-read + kernel boundary).
// Block = 4 waves, owns (i-strip 16, cg, bh); grid (24,4,16) = 1536 blocks.
// Per 64-j chunk (6 chunks):
//   SCORE: wave w computes S_c (ALL 4 c) for its own 16-j subtile via MFMA
//          (C-frags in-register -> gate needs no cross-wave S exchange).
//   GATE:  16 sigmoids/lane -> f16 into LDS gbuf laid out EXACTLY as MFMA
//          A-frags [c][ks][quad][mr][e] (cheap b16 writes, contiguous reads).
//   PV:    wave w=c: aa = gbuf frag, acc[nt] += mfma(aa, Z0 frag) (Z0 frags
//          hoisted to chunk start to hide HBM/L2 latency under score MFMA).
// Epilogue = proven pv_combine path: signed-qhat, ds_swizzle b-reduce,
// LDS Klein combine, packed bf16 CTXB store.
// Score/gate are recomputed per cg block (4x, ~0.6us of MFMA issue) - the
// price of 4x wave-parallelism without inter-block sync.
// ---------------------------------------------------------------------------
__global__ __launch_bounds__(256) void gate_pv(
    const _Float16* __restrict__ qhh, const _Float16* __restrict__ khh,
    const _Float16* __restrict__ Z0, const float* __restrict__ dde_w,
    const float* __restrict__ dde_b, unsigned short* __restrict__ CTXB)
{
  __shared__ _Float16 gbuf[4096];       // [c][ks2][quad][mr][e] A-frag packed
  __shared__ float vxs[4][4][16][4];    // [c][e][il][nt]
  __shared__ float qs[16][17];          // qhat f32 for epilogue, +1 pad

  const int tid = threadIdx.x, w = tid >> 6, lane = tid & 63;
  const int mr = lane & 15, quad = lane >> 4;
  const int bh = blockIdx.z, cg = blockIdx.y, ib = blockIdx.x;
  const int i0 = ib * 16;

  {  // stage qhat f32 (this cg's 4 atoms x 16 rows) for the epilogue
    int il = tid >> 4, t = tid & 15;
    qs[il][t] = (float)qhh[pidx(bh * L_SEQ + i0 + il, cg * 16 + t, 64)];
  }

  float wn[16], bn[4];
  #pragma unroll
  for (int t = 0; t < 16; ++t) wn[t] = uniform_f(dde_w[t]) * (-LOG2E * 0.0625f);
  #pragma unroll
  for (int c = 0; c < 4; ++c) bn[c] = uniform_f(dde_b[c]) * (-LOG2E);

  // score A-frags R_c(qhat) for the i-strip (built once; 32 VGPR)
  u4h8 fr[4][2];
  {
    const _Float16* ap = qhh + ((size_t)(bh * 24 + ib)) * 2 * 512 + lane * 8;
    #pragma unroll
    for (int ks = 0; ks < 2; ++ks) {
      uint4 qa = *(const uint4*)(ap + ks * 512);
      unsigned s0 = ror16(qa.x), s1 = ror16(qa.y), s2 = ror16(qa.z), s3 = ror16(qa.w);
      // R0=(w,-x,-y,-z)  R1=(x,w,-z,y)  R2=(y,z,w,-x)  R3=(z,-y,x,w)
      fr[0][ks].u = make_uint4(qa.x ^ 0x80000000u, qa.y ^ 0x80008000u,
                               qa.z ^ 0x80000000u, qa.w ^ 0x80008000u);
      fr[1][ks].u = make_uint4(s0, s1 ^ 0x00008000u, s2, s3 ^ 0x00008000u);
      fr[2][ks].u = make_uint4(qa.y, qa.x ^ 0x80000000u, qa.w, qa.z ^ 0x80000000u);
      fr[3][ks].u = make_uint4(s1 ^ 0x80000000u, s0, s3 ^ 0x80000000u, s2);
    }
  }

  const int bq = mr >> 2, e = mr & 3;
  // sgn_c(b) nibbles {E,4,8,2} -> 0x284E; tau(c,e) nibbles {0,A,6,C} -> 0xC6A0
  const unsigned msk =
      ((((0x284Eu >> (w * 4 + bq)) ^ (0xC6A0u >> (w * 4 + e))) & 1u) << 31);

  f32x4 acc[4];                          // PV accumulators (c=w, 4 n-tiles)
  #pragma unroll
  for (int nt = 0; nt < 4; ++nt) acc[nt] = (f32x4){0.f, 0.f, 0.f, 0.f};

  const int jl = w * 16 + mr;            // this lane's j within the chunk
  const int gw = (jl >> 3) * 128 + (jl & 7) + quad * 32;  // gbuf write base (+c*1024+r*8)

  for (int ch = 0; ch < 6; ++ch) {
    // hoist PV Z0 frags (independent of score) to hide load latency
    u4h8 zb[2][4];
    #pragma unroll
    for (int ks2 = 0; ks2 < 2; ++ks2)
      #pragma unroll
      for (int nt = 0; nt < 4; ++nt)
        zb[ks2][nt].h = *(const f16x8*)(Z0 + (size_t)bh * (256 * 384)
                         + (((size_t)(cg * 4 + nt) * 12 + ch * 2 + ks2) * 512) + lane * 8);

    // SCORE: wave w's 16-j subtile, all 4 c
    const _Float16* bp = khh + ((size_t)(bh * 24 + ch * 4 + w)) * 2 * 512 + lane * 8;
    u4h8 kb[2];
    kb[0].h = *(const f16x8*)(bp);
    kb[1].h = *(const f16x8*)(bp + 512);
    f32x4 accS[4];
    #pragma unroll
    for (int c = 0; c < 4; ++c) {
      accS[c] = (f32x4){0.f, 0.f, 0.f, 0.f};
      accS[c] = __builtin_amdgcn_mfma_f32_16x16x32_f16(fr[c][0].h, kb[0].h, accS[c], 0, 0, 0);
      accS[c] = __builtin_amdgcn_mfma_f32_16x16x32_f16(fr[c][1].h, kb[1].h, accS[c], 0, 0, 0);
    }

    // GATE: 16 sigmoids -> f16 A-frag positions in LDS
    #pragma unroll
    for (int r = 0; r < 4; ++r) {
      float S0 = accS[0][r], S1 = accS[1][r], S2 = accS[2][r], S3 = accS[3][r];
      #pragma unroll
      for (int c = 0; c < 4; ++c) {
        float n = bn[c] + wn[c*4+0]*S0 + wn[c*4+1]*S1 + wn[c*4+2]*S2 + wn[c*4+3]*S3;
        float g = __builtin_amdgcn_rcpf(1.f + __builtin_amdgcn_exp2f(n));
        gbuf[c * 1024 + gw + r * 8] = (_Float16)g;
      }
    }
    __syncthreads();

    // PV: wave w = c; contiguous 1KB/wave gbuf reads (conflict-free)
    #pragma unroll
    for (int ks2 = 0; ks2 < 2; ++ks2) {
      f16x8 aa = *(const f16x8*)&gbuf[(w * 2 + ks2) * 512 + lane * 8];
      #pragma unroll
      for (int nt = 0; nt < 4; ++nt)
        acc[nt] = __builtin_amdgcn_mfma_f32_16x16x32_f16(aa, zb[ks2][nt].h, acc[nt], 0, 0, 0);
    }
    __syncthreads();   // protect gbuf before next chunk's writes
  }

  // EPILOGUE: signed-q multiply + b-reduce (lanes ^4, ^8), deposit V_c[e]
  #pragma unroll
  for (int nt = 0; nt < 4; ++nt) {
    #pragma unroll
    for (int r = 0; r < 4; ++r) {
      int il = quad * 4 + r;
      float sq = __uint_as_float(__float_as_uint(qs[il][nt * 4 + (bq ^ w)]) ^ msk);
      float v = sq * acc[nt][r];
      v += swz_xor<0x101F>(v);
      v += swz_xor<0x201F>(v);
      if (bq == 0) vxs[w][e][il][nt] = v;
    }
  }
  __syncthreads();

  {  // final Klein combine: ctx_d = sum_c V_c[c^d]; packed bf16 store
    int il = tid >> 4, cc = tid & 15, nt = cc >> 2, d = cc & 3;
    float s = vxs[0][d][il][nt] + vxs[1][1 ^ d][il][nt] +
              vxs[2][2 ^ d][il][nt] + vxs[3][3 ^ d][il][nt];
    int bb_ = bh >> 3, hh = bh & 7;
    CTXB[pidx(bb_ * L_SEQ + i0 + il, hh * HD + cg * 16 + nt * 4 + d, 512)] =
        (unsigned short)f2bf(s);
  }
}

// ---------------------------------------------------------------------------
// Workspace (<= 8,388,608 B used):
//   [0        ..   524288)  Wob bf16 packed                [whole run]
//   [524288   ..  1310720)  qhat f16 packed                [gemm -> gate_pv]
//   [1310720  ..  2097152)  khat f16 packed                [gemm -> gate_pv]
//   [2097152  ..  5242880)  Z0 f16 packed                  [z_build -> gate_pv]
//   [5242880  ..  6029312)  vhat f16 [gemm -> z_build] | CTXB bf16 [gate_pv -> out]
//   [6029312  ..  8388608)  xb|Wqb|Wkb|Wvb bf16 packed     [cvt -> gemm]
// (CTXB moved out of the khat alias: the fused kernel reads khat to its end.)
// ---------------------------------------------------------------------------
extern "C" void kernel_launch(void* const* d_in, const int* in_sizes, int n_in,
                              void* d_out, int out_size, void* d_ws, size_t ws_size,
                              hipStream_t stream)
{
  const float* x     = (const float*)d_in[0];
  const float* Wq    = (const float*)d_in[1];
  const float* Wk    = (const float*)d_in[2];
  const float* Wv    = (const float*)d_in[3];
  const float* Wo    = (const float*)d_in[4];
  const float* dde_w = (const float*)d_in[5];
  const float* dde_b = (const float*)d_in[6];
  float* out = (float*)d_out;

  char* ws = (char*)d_ws;
  unsigned short* Wob  = (unsigned short*)(ws + 0);
  _Float16* qhh = (_Float16*)(ws + 524288);
  _Float16* khh = (_Float16*)(ws + 1310720);
  _Float16* Z0h = (_Float16*)(ws + 2097152);
  _Float16* vhh = (_Float16*)(ws + 5242880);
  unsigned short* CTXB = (unsigned short*)(ws + 5242880);
  unsigned short* xb  = (unsigned short*)(ws + 6029312);
  unsigned short* Wqb = (unsigned short*)(ws + 6815744);
  unsigned short* Wkb = (unsigned short*)(ws + 7340032);
  unsigned short* Wvb = (unsigned short*)(ws + 7864320);

  // 1) fp32 -> bf16 conversions (packed) + zero `out`
  to_bf16_all<<<1792, 256, 0, stream>>>(x, Wq, Wk, Wv, Wo, xb, Wob, out);

  // 2) Q/K/V projections + fused per-atom normalize -> packed f16 (1152 blocks)
  gemm_mfma<1, 1><<<dim3(32, 12, 3), 256, 0, stream>>>(
      (const __bf16*)xb, (const __bf16*)Wqb, (const __bf16*)Wkb, (const __bf16*)Wvb,
      (float*)qhh, (float*)khh, (float*)vhh, 2 * L_SEQ, E_DIM, E_DIM);

  // 3) PV operand Z0 = khat_b * v_e
  z_build<<<dim3(6, 4, 16), 256, 0, stream>>>(khh, vhh, Z0h);

  // 4) FUSED score+gate+PV -> packed CTXB bf16 (no G tensor)
  gate_pv<<<dim3(24, 4, 16), 256, 0, stream>>>(qhh, khh, Z0h, dde_w, dde_b, CTXB);

  // 5) output projection: K-split x4, f32 atomic-add (768 blocks)
  gemm_mfma<2, 2><<<dim3(16, 12, 4), 256, 0, stream>>>(
      (const __bf16*)CTXB, (const __bf16*)Wob, nullptr, nullptr,
      out, nullptr, nullptr, 2 * L_SEQ, E_DIM, E_DIM);
}

// Round 7
// 102.792 us; speedup vs baseline: 1.7600x; 1.0707x over previous
//
#include <hip/hip_runtime.h>
#include <math.h>

#define L_SEQ 384
#define E_DIM 512
#define NHEAD 8
#define NBH   16
#define HD    64
#define LOG2E 1.44269504f

typedef __attribute__((ext_vector_type(8))) __bf16 bf16x8;
typedef __attribute__((ext_vector_type(8))) _Float16 f16x8;
typedef __attribute__((ext_vector_type(4))) float f32x4;

union u4h8 { uint4 u; f16x8 h; };

__device__ __forceinline__ float uniform_f(float v) {
  return __uint_as_float(__builtin_amdgcn_readfirstlane(__float_as_uint(v)));
}

__device__ __forceinline__ unsigned f2bf(float f) {   // RNE float->bf16 bits
  unsigned u = __float_as_uint(f);
  return (u + 0x7FFFu + ((u >> 16) & 1u)) >> 16;
}

__device__ __forceinline__ unsigned ror16(unsigned x) { return (x >> 16) | (x << 16); }

// quad_perm DPP: butterfly over the 4 lanes of each aligned 4-lane group
__device__ __forceinline__ float dpp_xor1(float x) {
  return __int_as_float(__builtin_amdgcn_mov_dpp(__float_as_int(x), 0xB1, 0xF, 0xF, 0));
}
__device__ __forceinline__ float dpp_xor2(float x) {
  return __int_as_float(__builtin_amdgcn_mov_dpp(__float_as_int(x), 0x4E, 0xF, 0xF, 0));
}
template <int IMM>
__device__ __forceinline__ float swz_xor(float x) {   // ds_swizzle: imm must be literal
  return __int_as_float(__builtin_amdgcn_ds_swizzle(__float_as_int(x), IMM));
}

// Fragment-packed layout: a wave consumes one (16-row x 32-k) tile as
// lane(quad,mr) -> row=mr, k=quad*8..+7. Pack memory in exactly that order:
// [row/16][k/32][quad=(k>>3)&3][mr=row&15][e=k&7] -> coalesced 16B/lane loads.
__device__ __forceinline__ size_t pidx(int row, int k, int Kd) {
  return ((((size_t)(row >> 4) * (Kd >> 5) + (k >> 5)) * 4 + ((k >> 3) & 3)) * 16
          + (row & 15)) * 8 + (k & 7);
}

// ---------------------------------------------------------------------------
// Convert x|Wq|Wk|Wv (dst1) and Wo (dst2) to bf16 packed; also zero `out`
// (needed by the K-split atomic out-gemm; this kernel runs first).
// ---------------------------------------------------------------------------
__global__ __launch_bounds__(256) void to_bf16_all(
    const float* __restrict__ x, const float* __restrict__ Wq,
    const float* __restrict__ Wk, const float* __restrict__ Wv,
    const float* __restrict__ Wo, unsigned short* __restrict__ dst1,
    unsigned short* __restrict__ dst2, float* __restrict__ outz)
{
  int e0 = (blockIdx.x * 256 + threadIdx.x) * 4;
  if (e0 >= 1835008) return;
  if (e0 >= 1441792) {                       // zero the output buffer
    *(float4*)(outz + (e0 - 1441792)) = make_float4(0.f, 0.f, 0.f, 0.f);
    return;
  }
  const float* src; unsigned short* d; int s;
  if (e0 < 393216)       { src = x;  s = e0;           d = dst1; }
  else if (e0 < 655360)  { src = Wq; s = e0 - 393216;  d = dst1 + 393216; }
  else if (e0 < 917504)  { src = Wk; s = e0 - 655360;  d = dst1 + 655360; }
  else if (e0 < 1179648) { src = Wv; s = e0 - 917504;  d = dst1 + 917504; }
  else                   { src = Wo; s = e0 - 1179648; d = dst2; }
  float4 v = *(const float4*)(src + s);
  unsigned lo = f2bf(v.x) | (f2bf(v.y) << 16);
  unsigned hi = f2bf(v.z) | (f2bf(v.w) << 16);
  int row = s >> 9, k = s & 511;
  *(uint2*)(d + pidx(row, k, 512)) = make_uint2(lo, hi);
}

// ---------------------------------------------------------------------------
// bf16 MFMA GEMM, packed-fragment operands. C = A @ B^T. tile 64m x (16*NTN)n.
// MODE 1 (QKV): z selects B/C; epilogue does per-atom quaternion normalize
//   (DPP quad-sum across the 4 lanes holding d..d+3) for z<2, then packed-f16
//   store (row=(b*8+h)*L+l, k=d, Kd=64).
// MODE 2 (out): z = K-split chunk (128 wide); f32 atomic-add epilogue.
// ---------------------------------------------------------------------------
template <int NTN, int MODE>
__global__ __launch_bounds__(256) void gemm_mfma(
    const __bf16* __restrict__ A, const __bf16* __restrict__ B0,
    const __bf16* __restrict__ B1, const __bf16* __restrict__ B2,
    float* __restrict__ C0, float* __restrict__ C1, float* __restrict__ C2,
    int M, int N, int K)
{
  const int z = blockIdx.z;
  const __bf16* Bm = (MODE == 2) ? B0 : (z == 0) ? B0 : (z == 1) ? B1 : B2;
  float* Cp = (MODE == 2) ? C0 : (z == 0) ? C0 : (z == 1) ? C1 : C2;

  const int tid = threadIdx.x;
  const int wave = tid >> 6, lane = tid & 63;
  const int m0 = blockIdx.y * 64 + wave * 16;
  const int n0 = blockIdx.x * (16 * NTN);
  const int mr = lane & 15, quad = lane >> 4;
  const int KT = K >> 5;
  const int kb0 = (MODE == 2) ? z * 4 : 0;   // K-split start (32-blocks)
  const int KL = (MODE == 2) ? 4 : KT;

  f32x4 acc[NTN];
  #pragma unroll
  for (int nt = 0; nt < NTN; ++nt) acc[nt] = (f32x4){0.f, 0.f, 0.f, 0.f};

  const __bf16* ap = A + ((size_t)(m0 >> 4) * KT + kb0) * 512 + lane * 8;
  const __bf16* bp = Bm + ((size_t)(n0 >> 4) * KT + kb0) * 512 + lane * 8;

  #pragma unroll 4
  for (int ks = 0; ks < KL; ++ks) {
    bf16x8 a = *(const bf16x8*)(ap + (size_t)ks * 512);
    #pragma unroll
    for (int nt = 0; nt < NTN; ++nt) {
      bf16x8 b = *(const bf16x8*)(bp + ((size_t)nt * KT + ks) * 512);
      acc[nt] = __builtin_amdgcn_mfma_f32_16x16x32_bf16(a, b, acc[nt], 0, 0, 0);
    }
  }

  if (MODE == 2) {
    #pragma unroll
    for (int nt = 0; nt < NTN; ++nt) {
      int n = n0 + nt * 16 + mr;
      #pragma unroll
      for (int r = 0; r < 4; ++r) {
        int m = m0 + quad * 4 + r;
        __hip_atomic_fetch_add(&Cp[(size_t)m * N + n], acc[nt][r],
                               __ATOMIC_RELAXED, __HIP_MEMORY_SCOPE_AGENT);
      }
    }
  } else {
    _Float16* Hp = (_Float16*)Cp;
    #pragma unroll
    for (int nt = 0; nt < NTN; ++nt) {
      int n = n0 + nt * 16 + mr;
      #pragma unroll
      for (int r = 0; r < 4; ++r) {
        float val = acc[nt][r];
        float s = val * val;
        s += dpp_xor1(s);
        s += dpp_xor2(s);          // |atom|^2 across the 4 component lanes
        float sc = (z == 2) ? 1.f : __builtin_amdgcn_rsqf(fmaxf(s, 1e-30f));
        int m = m0 + quad * 4 + r;
        int b = m / L_SEQ, l = m - b * L_SEQ;
        int row = (b * NHEAD + (n >> 6)) * L_SEQ + l;
        Hp[pidx(row, n & 63, 64)] = (_Float16)(val * sc);
      }
    }
  }
}

// ---------------------------------------------------------------------------
// z_build: Z0[bh][col=(a,b,e)][j] = khat_b(j,a) * v_e(j,a), packed f16.
// grid (6 j-blocks, 4 a-groups, 16 bh) x 256.
// ---------------------------------------------------------------------------
__global__ __launch_bounds__(256) void z_build(
    const _Float16* __restrict__ khh, const _Float16* __restrict__ vhh,
    _Float16* __restrict__ Z0)
{
  const int tid = threadIdx.x;
  const int l = blockIdx.x * 64 + (tid & 63);
  const int a = blockIdx.y * 4 + (tid >> 6);
  const int bh = blockIdx.z;

  size_t off = pidx(bh * L_SEQ + l, a * 4, 64);
  union { uint2 u; _Float16 h[4]; } kk, vv;
  kk.u = *(const uint2*)(khh + off);
  vv.u = *(const uint2*)(vhh + off);

  float kb[4] = {(float)kk.h[0], (float)kk.h[1], (float)kk.h[2], (float)kk.h[3]};
  float ve[4] = {(float)vv.h[0], (float)vv.h[1], (float)vv.h[2], (float)vv.h[3]};
  _Float16* zp = Z0 + (size_t)bh * (256 * 384);
  #pragma unroll
  for (int b = 0; b < 4; ++b)
    #pragma unroll
    for (int e = 0; e < 4; ++e)
      zp[pidx(a * 16 + b * 4 + e, l, 384)] = (_Float16)(kb[b] * ve[e]);
}

// ---------------------------------------------------------------------------
// gate_pv v2: fused score->gate->PV with SCORE COMPUTED ONCE (was 4x: the
// cg-per-BLOCK split recomputed 14.4 GF of score MFMA; now cg is per-WAVE).
// Block = 4 waves owns (i-strip 16, bh); grid (24, 16) = 384 blocks.
// Per 64-j chunk (6):
//   SCORE: wave w scores its own 16-j subtile for ALL 4 c (8 MFMA).
//   GATE:  16 sigmoids/lane -> f16 LDS gbuf in MFMA A-frag order
//          (double-buffered on ch&1 -> ONE barrier per chunk).
//   PV:    wave w owns cg=w: for all 4 c, acc[c][nt] += mfma(G_c, Z0_cg).
// Epilogue: R1-verified intra-wave Klein butterfly (signed-qhat multiply,
// ds_swizzle b-reduce, permuted dpp e-stages), lane mr==0 stores packed
// bf16 uint2 to CTXB. Total kernel FLOP 24 -> 9.6 GF.
// ---------------------------------------------------------------------------
__global__ __launch_bounds__(256) void gate_pv(
    const _Float16* __restrict__ qhh, const _Float16* __restrict__ khh,
    const _Float16* __restrict__ Z0, const float* __restrict__ dde_w,
    const float* __restrict__ dde_b, unsigned short* __restrict__ CTXB)
{
  __shared__ _Float16 gbuf[2][4096];    // [buf][c][ks2][quadk][row][e]
  __shared__ float qs[16][65];          // qhat f32, all 64 comps, +1 pad

  const int tid = threadIdx.x, w = tid >> 6, lane = tid & 63;
  const int mr = lane & 15, quad = lane >> 4;
  const int bh = blockIdx.y, ib = blockIdx.x;
  const int i0 = ib * 16;

  {  // stage qhat f32: 16 rows x 64 comps (4 comps/thread)
    int il = tid >> 4, k4 = (tid & 15) * 4;
    union { uint2 u; _Float16 h[4]; } cv;
    cv.u = *(const uint2*)(qhh + pidx(bh * L_SEQ + i0 + il, k4, 64));
    qs[il][k4 + 0] = (float)cv.h[0]; qs[il][k4 + 1] = (float)cv.h[1];
    qs[il][k4 + 2] = (float)cv.h[2]; qs[il][k4 + 3] = (float)cv.h[3];
  }

  float wn[16], bn[4];
  #pragma unroll
  for (int t = 0; t < 16; ++t) wn[t] = uniform_f(dde_w[t]) * (-LOG2E * 0.0625f);
  #pragma unroll
  for (int c = 0; c < 4; ++c) bn[c] = uniform_f(dde_b[c]) * (-LOG2E);

  // score A-frags R_c(qhat) for the i-strip (built once; 32 VGPR)
  u4h8 fr[4][2];
  {
    const _Float16* ap = qhh + ((size_t)(bh * 24 + ib)) * 2 * 512 + lane * 8;
    #pragma unroll
    for (int ks = 0; ks < 2; ++ks) {
      uint4 qa = *(const uint4*)(ap + ks * 512);
      unsigned s0 = ror16(qa.x), s1 = ror16(qa.y), s2 = ror16(qa.z), s3 = ror16(qa.w);
      // R0=(w,-x,-y,-z)  R1=(x,w,-z,y)  R2=(y,z,w,-x)  R3=(z,-y,x,w)
      fr[0][ks].u = make_uint4(qa.x ^ 0x80000000u, qa.y ^ 0x80008000u,
                               qa.z ^ 0x80000000u, qa.w ^ 0x80008000u);
      fr[1][ks].u = make_uint4(s0, s1 ^ 0x00008000u, s2, s3 ^ 0x00008000u);
      fr[2][ks].u = make_uint4(qa.y, qa.x ^ 0x80000000u, qa.w, qa.z ^ 0x80000000u);
      fr[3][ks].u = make_uint4(s1 ^ 0x80000000u, s0, s3 ^ 0x80000000u, s2);
    }
  }

  const int bq = mr >> 2, e = mr & 3;
  // sgn_c(b) nibbles {E,4,8,2} -> 0x284E; tau(c,e) nibbles {0,A,6,C} -> 0xC6A0
  unsigned msk[4];
  #pragma unroll
  for (int c = 0; c < 4; ++c)
    msk[c] = ((((0x284Eu >> (c * 4 + bq)) ^ (0xC6A0u >> (c * 4 + e))) & 1u) << 31);

  f32x4 acc[4][4];                       // [c][nt] PV accumulators (cg = w)
  #pragma unroll
  for (int c = 0; c < 4; ++c)
    #pragma unroll
    for (int nt = 0; nt < 4; ++nt) acc[c][nt] = (f32x4){0.f, 0.f, 0.f, 0.f};

  const int jl = w * 16 + mr;            // this lane's j within the chunk
  const int gw = (jl >> 3) * 128 + (jl & 7) + quad * 32;  // gbuf write base

  #pragma unroll 2
  for (int ch = 0; ch < 6; ++ch) {
    // PV Z0 frags for wave's cg=w slice (independent of score: hoisted)
    u4h8 zb[2][4];
    #pragma unroll
    for (int ks2 = 0; ks2 < 2; ++ks2)
      #pragma unroll
      for (int nt = 0; nt < 4; ++nt)
        zb[ks2][nt].h = *(const f16x8*)(Z0 + (size_t)bh * (256 * 384)
                         + (((size_t)(w * 4 + nt) * 12 + ch * 2 + ks2) * 512) + lane * 8);

    // SCORE: wave w's 16-j subtile, all 4 c (computed ONCE per (i,j,c))
    const _Float16* bp = khh + ((size_t)(bh * 24 + ch * 4 + w)) * 2 * 512 + lane * 8;
    u4h8 kb[2];
    kb[0].h = *(const f16x8*)(bp);
    kb[1].h = *(const f16x8*)(bp + 512);
    f32x4 accS[4];
    #pragma unroll
    for (int c = 0; c < 4; ++c) {
      accS[c] = (f32x4){0.f, 0.f, 0.f, 0.f};
      accS[c] = __builtin_amdgcn_mfma_f32_16x16x32_f16(fr[c][0].h, kb[0].h, accS[c], 0, 0, 0);
      accS[c] = __builtin_amdgcn_mfma_f32_16x16x32_f16(fr[c][1].h, kb[1].h, accS[c], 0, 0, 0);
    }

    // GATE: 16 sigmoids -> f16 A-frag positions in LDS (buffer ch&1)
    #pragma unroll
    for (int r = 0; r < 4; ++r) {
      float S0 = accS[0][r], S1 = accS[1][r], S2 = accS[2][r], S3 = accS[3][r];
      #pragma unroll
      for (int c = 0; c < 4; ++c) {
        float n = bn[c] + wn[c*4+0]*S0 + wn[c*4+1]*S1 + wn[c*4+2]*S2 + wn[c*4+3]*S3;
        float g = __builtin_amdgcn_rcpf(1.f + __builtin_amdgcn_exp2f(n));
        gbuf[ch & 1][c * 1024 + gw + r * 8] = (_Float16)g;
      }
    }
    __syncthreads();                     // single barrier/chunk (dbuf'd gbuf)

    // PV: wave w = cg; all 4 c against its Z0 slice
    #pragma unroll
    for (int ks2 = 0; ks2 < 2; ++ks2) {
      #pragma unroll
      for (int c = 0; c < 4; ++c) {
        f16x8 aa = *(const f16x8*)&gbuf[ch & 1][c * 1024 + ks2 * 512 + lane * 8];
        #pragma unroll
        for (int nt = 0; nt < 4; ++nt)
          acc[c][nt] = __builtin_amdgcn_mfma_f32_16x16x32_f16(aa, zb[ks2][nt].h, acc[c][nt], 0, 0, 0);
      }
    }
  }

  // EPILOGUE (intra-wave, R1-verified): signed-q multiply, b-reduce (^4,^8),
  // permuted e-stages; lane mr==0 holds ctx_d in r_d -> packed bf16 store.
  const int bb_ = bh >> 3, hh = bh & 7;
  #pragma unroll
  for (int nt = 0; nt < 4; ++nt) {
    #pragma unroll
    for (int r = 0; r < 4; ++r) {
      int il = quad * 4 + r;
      float pb[4];
      #pragma unroll
      for (int c = 0; c < 4; ++c) {
        float sq = __uint_as_float(
            __float_as_uint(qs[il][w * 16 + nt * 4 + (bq ^ c)]) ^ msk[c]);
        float v = sq * acc[c][nt][r];
        v += swz_xor<0x101F>(v);
        v += swz_xor<0x201F>(v);
        pb[c] = v;
      }
      float q0 = pb[0] + dpp_xor1(pb[1]);
      float q1 = pb[1] + dpp_xor1(pb[0]);
      float q2 = pb[2] + dpp_xor1(pb[3]);
      float q3 = pb[3] + dpp_xor1(pb[2]);
      float r0 = q0 + dpp_xor2(q2);
      float r1 = q1 + dpp_xor2(q3);
      float r2 = q2 + dpp_xor2(q0);
      float r3 = q3 + dpp_xor2(q1);
      if (mr == 0) {
        unsigned lo = f2bf(r0) | (f2bf(r1) << 16);
        unsigned hi = f2bf(r2) | (f2bf(r3) << 16);
        *(uint2*)&CTXB[pidx(bb_ * L_SEQ + i0 + il,
                            hh * HD + w * 16 + nt * 4, 512)] = make_uint2(lo, hi);
      }
    }
  }
}

// ---------------------------------------------------------------------------
// Workspace (<= 8,388,608 B used):
//   [0        ..   524288)  Wob bf16 packed                [whole run]
//   [524288   ..  1310720)  qhat f16 packed                [gemm -> gate_pv]
//   [1310720  ..  2097152)  khat f16 packed                [gemm -> gate_pv]
//   [2097152  ..  5242880)  Z0 f16 packed                  [z_build -> gate_pv]
//   [5242880  ..  6029312)  vhat f16 [gemm -> z_build] | CTXB bf16 [gate_pv -> out]
//   [6029312  ..  8388608)  xb|Wqb|Wkb|Wvb bf16 packed     [cvt -> gemm]
// ---------------------------------------------------------------------------
extern "C" void kernel_launch(void* const* d_in, const int* in_sizes, int n_in,
                              void* d_out, int out_size, void* d_ws, size_t ws_size,
                              hipStream_t stream)
{
  const float* x     = (const float*)d_in[0];
  const float* Wq    = (const float*)d_in[1];
  const float* Wk    = (const float*)d_in[2];
  const float* Wv    = (const float*)d_in[3];
  const float* Wo    = (const float*)d_in[4];
  const float* dde_w = (const float*)d_in[5];
  const float* dde_b = (const float*)d_in[6];
  float* out = (float*)d_out;

  char* ws = (char*)d_ws;
  unsigned short* Wob  = (unsigned short*)(ws + 0);
  _Float16* qhh = (_Float16*)(ws + 524288);
  _Float16* khh = (_Float16*)(ws + 1310720);
  _Float16* Z0h = (_Float16*)(ws + 2097152);
  _Float16* vhh = (_Float16*)(ws + 5242880);
  unsigned short* CTXB = (unsigned short*)(ws + 5242880);
  unsigned short* xb  = (unsigned short*)(ws + 6029312);
  unsigned short* Wqb = (unsigned short*)(ws + 6815744);
  unsigned short* Wkb = (unsigned short*)(ws + 7340032);
  unsigned short* Wvb = (unsigned short*)(ws + 7864320);

  // 1) fp32 -> bf16 conversions (packed) + zero `out`
  to_bf16_all<<<1792, 256, 0, stream>>>(x, Wq, Wk, Wv, Wo, xb, Wob, out);

  // 2) Q/K/V projections + fused per-atom normalize -> packed f16 (1152 blocks)
  gemm_mfma<1, 1><<<dim3(32, 12, 3), 256, 0, stream>>>(
      (const __bf16*)xb, (const __bf16*)Wqb, (const __bf16*)Wkb, (const __bf16*)Wvb,
      (float*)qhh, (float*)khh, (float*)vhh, 2 * L_SEQ, E_DIM, E_DIM);

  // 3) PV operand Z0 = khat_b * v_e
  z_build<<<dim3(6, 4, 16), 256, 0, stream>>>(khh, vhh, Z0h);

  // 4) FUSED score+gate+PV, score-once -> packed CTXB bf16
  gate_pv<<<dim3(24, 16), 256, 0, stream>>>(qhh, khh, Z0h, dde_w, dde_b, CTXB);

  // 5) output projection: K-split x4, f32 atomic-add (768 blocks)
  gemm_mfma<2, 2><<<dim3(16, 12, 4), 256, 0, stream>>>(
      (const __bf16*)CTXB, (const __bf16*)Wob, nullptr, nullptr,
      out, nullptr, nullptr, 2 * L_SEQ, E_DIM, E_DIM);
}